// Round 1
// baseline (532.380 us; speedup 1.0000x reference)
//
#include <hip/hip_runtime.h>

// ---------------------------------------------------------------------------
// MultiHeadedAttention w/ n-gram RNN heads + rel-pos embeddings. MFMA version.
// B=8 S=512 D=1024 H=8 DPH=128, MAX_REL=32, NG heads 4..7.
// R10: fused scores+softmax+AV kernel (swapped-operand QK so attn lives
// k-major per thread: float4 attn stores, LDS-resident bf16 attn tile feeds
// the AV MFMAs directly -- kills av_ctx's 67MB fp32 re-read + abuf round-trip).
// Buckets (r=0 / r=64) kept in registers, applied vs fp32 rel in epilogue.
//
// ws (33,595,648 B): qb | kb | vT | ctx | relb | relT.
// d_out attn-region scratch (dead before fused kernel overwrites with attn):
//   xb | vb | rnnout | Wqkvb | Wrnnb.
// ---------------------------------------------------------------------------

typedef __bf16 bf16x8 __attribute__((ext_vector_type(8)));
typedef float f32x4 __attribute__((ext_vector_type(4)));

#define MFMA16(a, b, c) __builtin_amdgcn_mfma_f32_16x16x32_bf16(a, b, c, 0, 0, 0)

__device__ __forceinline__ unsigned short f2bf(float f) {
  unsigned u = __float_as_uint(f);
  u += 0x7FFFu + ((u >> 16) & 1u);
  return (unsigned short)(u >> 16);
}
__device__ __forceinline__ uint2 pack4(float4 f) {
  uint2 r;
  r.x = (unsigned)f2bf(f.x) | ((unsigned)f2bf(f.y) << 16);
  r.y = (unsigned)f2bf(f.z) | ((unsigned)f2bf(f.w) << 16);
  return r;
}
// async 16B global->LDS DMA; dest = wave-uniform lds base + lane*16
__device__ __forceinline__ void gld16(const unsigned short* g, unsigned short* l) {
  __builtin_amdgcn_global_load_lds(
      (const __attribute__((address_space(1))) unsigned int*)g,
      (__attribute__((address_space(3))) unsigned int*)l, 16, 0, 0);
}

// ---------------------------------------------------------------------------
// K0: one-shot fp32->bf16 conversion of x, Wq|Wk|Wv, RNN weights.
// (Wo no longer pre-converted: out_proj stages fp32->bf16 on the fly.)
// ---------------------------------------------------------------------------
__global__ __launch_bounds__(256) void prep_bf16(
    const float* __restrict__ x,
    const float* __restrict__ Wq, const float* __restrict__ Wk,
    const float* __restrict__ Wv,
    const float* __restrict__ Wihf, const float* __restrict__ Whhf,
    const float* __restrict__ Wihb, const float* __restrict__ Whhb,
    unsigned short* __restrict__ xb, unsigned short* __restrict__ Wqkvb,
    unsigned short* __restrict__ Wrnnb) {
  int i = blockIdx.x * 256 + threadIdx.x;   // float4 index; grid exact 7232*256
  const float* src;
  unsigned short* dst;
  int off;
  if (i < 1048576) {                    // x
    src = x; dst = xb; off = i;
  } else if (i < 1310720) {             // Wq
    src = Wq; dst = Wqkvb; off = i - 1048576;
  } else if (i < 1572864) {             // Wk
    src = Wk; dst = Wqkvb + 1048576; off = i - 1310720;
  } else if (i < 1835008) {             // Wv
    src = Wv; dst = Wqkvb + 2097152; off = i - 1572864;
  } else if (i < 1839104) {             // Wihf
    src = Wihf; dst = Wrnnb; off = i - 1835008;
  } else if (i < 1843200) {             // Whhf
    src = Whhf; dst = Wrnnb + 16384; off = i - 1839104;
  } else if (i < 1847296) {             // Wihb
    src = Wihb; dst = Wrnnb + 32768; off = i - 1843200;
  } else {                              // Whhb
    src = Whhb; dst = Wrnnb + 49152; off = i - 1847296;
  }
  float4 f = *((const float4*)src + off);
  *(uint2*)(dst + (size_t)off * 4) = pack4(f);
}

// ---------------------------------------------------------------------------
// K1: QKV projection. 128x128 tiles, MFMA, DMA staging w/ rot8 swizzle.
// ---------------------------------------------------------------------------
__global__ __launch_bounds__(256) void qkv_proj(
    const unsigned short* __restrict__ xb, const unsigned short* __restrict__ Wqkvb,
    const float* __restrict__ bq, const float* __restrict__ bk,
    const float* __restrict__ bv, const int* __restrict__ mask,
    unsigned short* __restrict__ qb, unsigned short* __restrict__ kb,
    unsigned short* __restrict__ vb, unsigned short* __restrict__ vT) {
  __shared__ __align__(16) unsigned short As[128 * 64];
  __shared__ __align__(16) unsigned short Bs[128 * 64];
  const int bm = blockIdx.x & 31;
  const int bn = blockIdx.x >> 5;           // 0..23
  const int t = bn >> 3;                    // 0:q 1:k 2:v
  const int nloc0 = (bn & 7) * 128;
  const unsigned short* W = Wqkvb + (size_t)t * 1048576;
  const float* bias = (t == 0) ? bq : (t == 1) ? bk : bv;
  const int tid = threadIdx.x;
  const int lane = tid & 63, w = tid >> 6;
  const int wm = (w >> 1) * 64, wn = (w & 1) * 64;
  const int lanelo = lane & 15, quad = lane >> 4;
  const int row0 = bm * 128;
  const int rloc = lane >> 3, pch = lane & 7;
  const int lch = (pch - rloc) & 7;         // source chunk for rot8 swizzle

  f32x4 acc[4][4];
  const f32x4 zf = {0.f, 0.f, 0.f, 0.f};
#pragma unroll
  for (int i = 0; i < 4; ++i)
#pragma unroll
    for (int j = 0; j < 4; ++j) acc[i][j] = zf;

  for (int kt = 0; kt < 16; ++kt) {
#pragma unroll
    for (int q = 0; q < 4; ++q) {        // 16 segments of 8 rows; 4 per wave
      int seg = w * 4 + q;
      int grow = seg * 8 + rloc;
      gld16(xb + (size_t)(row0 + grow) * 1024 + kt * 64 + lch * 8, &As[seg * 512]);
      gld16(W + (size_t)(nloc0 + grow) * 1024 + kt * 64 + lch * 8, &Bs[seg * 512]);
    }
    __syncthreads();
#pragma unroll
    for (int ks = 0; ks < 2; ++ks) {
      const int pA = (ks * 4 + quad + lanelo) & 7;   // rotated phys chunk
      bf16x8 a[4], bb[4];
#pragma unroll
      for (int i = 0; i < 4; ++i)
        a[i] = *(const bf16x8*)(&As[(wm + i * 16 + lanelo) * 64 + pA * 8]);
#pragma unroll
      for (int j = 0; j < 4; ++j)
        bb[j] = *(const bf16x8*)(&Bs[(wn + j * 16 + lanelo) * 64 + pA * 8]);
#pragma unroll
      for (int i = 0; i < 4; ++i)
#pragma unroll
        for (int j = 0; j < 4; ++j) acc[i][j] = MFMA16(a[i], bb[j], acc[i][j]);
    }
    __syncthreads();
  }
#pragma unroll
  for (int i = 0; i < 4; ++i) {
#pragma unroll
    for (int j = 0; j < 4; ++j) {
      int jj = nloc0 + wn + j * 16 + lanelo;   // 0..1023 within tensor
      int hh = jj >> 7, dc = jj & 127;
      float bvv = bias[jj];
      int m0 = row0 + wm + i * 16 + quad * 4;
      int b0 = m0 >> 9, sS = m0 & 511;
      unsigned short ov[4];
#pragma unroll
      for (int r = 0; r < 4; ++r) {
        int s = sS + r;
        float val = acc[i][j][r] + bvv;
        if (mask[b0 * 512 + s]) val = 0.f;
        unsigned short o = f2bf(val);
        ov[r] = o;
        size_t off = ((size_t)(b0 * 8 + hh) * 512 + s) * 128 + dc;
        if (t == 0) qb[off] = o;
        else if (t == 1) kb[off] = o;
        else vb[off] = o;
      }
      if (t == 2) {
        uint2 pk;
        pk.x = (unsigned)ov[0] | ((unsigned)ov[1] << 16);
        pk.y = (unsigned)ov[2] | ((unsigned)ov[3] << 16);
        *(uint2*)(&vT[((size_t)(b0 * 8 + hh) * 128 + dc) * 512 + sS]) = pk;
      }
    }
  }
}

// ---------------------------------------------------------------------------
// K2: rel prep: relb (65x128 bf16 row-major), relT (128x96 bf16, zero-pad).
// ---------------------------------------------------------------------------
__global__ __launch_bounds__(256) void prep_rel(
    const float* __restrict__ rel, unsigned short* __restrict__ relb,
    unsigned short* __restrict__ relT) {
  int i = blockIdx.x * 256 + threadIdx.x;
  if (i < 65 * 128) relb[i] = f2bf(rel[i]);
  if (i < 128 * 96) {
    int d = i / 96, r = i - d * 96;
    relT[i] = (r < 65) ? f2bf(rel[r * 128 + d]) : (unsigned short)0;
  }
}

// ---------------------------------------------------------------------------
// K3: fused bidirectional 2-step RNN. MFMA. LDS rows padded 128->136.
// ---------------------------------------------------------------------------
__global__ __launch_bounds__(256) void rnn_fused(
    const unsigned short* __restrict__ qb, const unsigned short* __restrict__ kb,
    const unsigned short* __restrict__ vb,
    const unsigned short* __restrict__ Wrnnb,
    const float* __restrict__ bihf, const float* __restrict__ bhhf,
    const float* __restrict__ bihb, const float* __restrict__ bhhb,
    unsigned short* __restrict__ rnn_out) {
  __shared__ __align__(16) unsigned short X[65 * 136];   // rows s0-1 .. s0+63
  __shared__ __align__(16) unsigned short Wi[128 * 136];
  __shared__ __align__(16) unsigned short Wh[128 * 136];
  __shared__ __align__(16) unsigned short H1[64 * 136];
  __shared__ float cbf[128], cbb[128];

  const unsigned short* Wihfb = Wrnnb;
  const unsigned short* Whhfb = Wrnnb + 16384;
  const unsigned short* Wihbb = Wrnnb + 32768;
  const unsigned short* Whhbb = Wrnnb + 49152;

  const int gid = blockIdx.x;
  const int tile = gid & 7;
  const int g = gid >> 3;              // 0..95
  const int t = g >> 5;
  const int rem = g & 31;
  const int b = rem >> 2, h = (rem & 3) + 4;
  const int s0 = tile * 64;
  const unsigned short* src = (t == 0) ? qb : (t == 1) ? kb : vb;
  const size_t rowbase = (size_t)(b * 8 + h) * 512;
  const int tid = threadIdx.x;

  for (int c = tid; c < 65 * 16; c += 256) {   // X: 65 rows x 16 chunks
    int r = c >> 4, cc = c & 15;
    uint4 v4;
    if (r == 0 && s0 == 0) v4 = make_uint4(0, 0, 0, 0);
    else v4 = *(const uint4*)(src + (rowbase + (s0 - 1 + r)) * 128 + cc * 8);
    *(uint4*)(&X[r * 136 + cc * 8]) = v4;
  }
#pragma unroll
  for (int p = 0; p < 8; ++p) {       // weights: 2048 chunks of 8 bf16 each
    int c = p * 256 + tid;
    int r = c >> 4, cc = c & 15;
    *(uint4*)(&Wi[r * 136 + cc * 8]) = *(const uint4*)(Wihfb + c * 8);
    *(uint4*)(&Wh[r * 136 + cc * 8]) = *(const uint4*)(Whhfb + c * 8);
  }
  if (tid < 128) {
    cbf[tid] = bihf[tid] + bhhf[tid];
    cbb[tid] = bihb[tid] + bhhb[tid];
  }
  __syncthreads();

  const int lane = tid & 63, w = tid >> 6;
  const int lanelo = lane & 15, quad = lane >> 4;
  const int marow = w * 16 + lanelo;
  const f32x4 zf = {0.f, 0.f, 0.f, 0.f};

  // ---- forward h1 = tanh(Wihf x_{s-1} + cbf) ----
  f32x4 g1[8];
#pragma unroll
  for (int j = 0; j < 8; ++j) g1[j] = zf;
#pragma unroll
  for (int ks = 0; ks < 4; ++ks) {
    bf16x8 a = *(const bf16x8*)(&X[marow * 136 + ks * 32 + quad * 8]);
#pragma unroll
    for (int j = 0; j < 8; ++j) {
      bf16x8 bb = *(const bf16x8*)(&Wi[(j * 16 + lanelo) * 136 + ks * 32 + quad * 8]);
      g1[j] = MFMA16(a, bb, g1[j]);
    }
  }
#pragma unroll
  for (int j = 0; j < 8; ++j) {
    int col = j * 16 + lanelo;
    float cb = cbf[col];
#pragma unroll
    for (int i = 0; i < 4; ++i) {
      int row = w * 16 + quad * 4 + i;
      H1[row * 136 + col] = f2bf(tanhf(g1[j][i] + cb));
    }
  }
  __syncthreads();
  // ---- forward out = tanh(Wihf x_s + Whhf h1 + cbf) ----
  f32x4 a2[8];
#pragma unroll
  for (int j = 0; j < 8; ++j) a2[j] = zf;
#pragma unroll
  for (int ks = 0; ks < 4; ++ks) {
    bf16x8 a = *(const bf16x8*)(&X[(marow + 1) * 136 + ks * 32 + quad * 8]);
#pragma unroll
    for (int j = 0; j < 8; ++j) {
      bf16x8 bb = *(const bf16x8*)(&Wi[(j * 16 + lanelo) * 136 + ks * 32 + quad * 8]);
      a2[j] = MFMA16(a, bb, a2[j]);
    }
  }
#pragma unroll
  for (int ks = 0; ks < 4; ++ks) {
    bf16x8 a = *(const bf16x8*)(&H1[marow * 136 + ks * 32 + quad * 8]);
#pragma unroll
    for (int j = 0; j < 8; ++j) {
      bf16x8 bb = *(const bf16x8*)(&Wh[(j * 16 + lanelo) * 136 + ks * 32 + quad * 8]);
      a2[j] = MFMA16(a, bb, a2[j]);
    }
  }
  float outF[8][4];
#pragma unroll
  for (int j = 0; j < 8; ++j) {
    int col = j * 16 + lanelo;
    float cb = cbf[col];
#pragma unroll
    for (int i = 0; i < 4; ++i) outF[j][i] = tanhf(a2[j][i] + cb);
  }
  __syncthreads();
#pragma unroll
  for (int p = 0; p < 8; ++p) {   // restage backward weights
    int c = p * 256 + tid;
    int r = c >> 4, cc = c & 15;
    *(uint4*)(&Wi[r * 136 + cc * 8]) = *(const uint4*)(Wihbb + c * 8);
    *(uint4*)(&Wh[r * 136 + cc * 8]) = *(const uint4*)(Whhbb + c * 8);
  }
  __syncthreads();
  // ---- backward h1b = tanh(Wihb x_s + cbb) ----
#pragma unroll
  for (int j = 0; j < 8; ++j) g1[j] = zf;
#pragma unroll
  for (int ks = 0; ks < 4; ++ks) {
    bf16x8 a = *(const bf16x8*)(&X[(marow + 1) * 136 + ks * 32 + quad * 8]);
#pragma unroll
    for (int j = 0; j < 8; ++j) {
      bf16x8 bb = *(const bf16x8*)(&Wi[(j * 16 + lanelo) * 136 + ks * 32 + quad * 8]);
      g1[j] = MFMA16(a, bb, g1[j]);
    }
  }
#pragma unroll
  for (int j = 0; j < 8; ++j) {
    int col = j * 16 + lanelo;
    float cb = cbb[col];
#pragma unroll
    for (int i = 0; i < 4; ++i) {
      int row = w * 16 + quad * 4 + i;
      H1[row * 136 + col] = f2bf(tanhf(g1[j][i] + cb));
    }
  }
  __syncthreads();
  // ---- backward out + combine + store ----
#pragma unroll
  for (int j = 0; j < 8; ++j) a2[j] = zf;
#pragma unroll
  for (int ks = 0; ks < 4; ++ks) {
    bf16x8 a = *(const bf16x8*)(&X[marow * 136 + ks * 32 + quad * 8]);
#pragma unroll
    for (int j = 0; j < 8; ++j) {
      bf16x8 bb = *(const bf16x8*)(&Wi[(j * 16 + lanelo) * 136 + ks * 32 + quad * 8]);
      a2[j] = MFMA16(a, bb, a2[j]);
    }
  }
#pragma unroll
  for (int ks = 0; ks < 4; ++ks) {
    bf16x8 a = *(const bf16x8*)(&H1[marow * 136 + ks * 32 + quad * 8]);
#pragma unroll
    for (int j = 0; j < 8; ++j) {
      bf16x8 bb = *(const bf16x8*)(&Wh[(j * 16 + lanelo) * 136 + ks * 32 + quad * 8]);
      a2[j] = MFMA16(a, bb, a2[j]);
    }
  }
#pragma unroll
  for (int j = 0; j < 8; ++j) {
    int col = j * 16 + lanelo;
    float cb = cbb[col];
#pragma unroll
    for (int i = 0; i < 4; ++i) {
      int row = w * 16 + quad * 4 + i;
      float val = outF[j][i] + tanhf(a2[j][i] + cb);
      rnn_out[((size_t)g * 512 + s0 + row) * 128 + col] = f2bf(val);
    }
  }
}

// ---------------------------------------------------------------------------
// K4: copy rnn results back into qb/kb (+vT for v).
// ---------------------------------------------------------------------------
__global__ __launch_bounds__(256) void rnn_copyback(
    const unsigned short* __restrict__ rnn_out,
    unsigned short* __restrict__ qb, unsigned short* __restrict__ kb,
    unsigned short* __restrict__ vT) {
  int idx = blockIdx.x * 256 + threadIdx.x;   // 6,291,456
  int g = idx >> 16;
  int r2 = idx & 65535;
  int s = r2 >> 7, col = r2 & 127;
  int t = g >> 5, rem = g & 31, b = rem >> 2, h = (rem & 3) + 4;
  unsigned short val = rnn_out[idx];
  size_t off = ((size_t)(b * 8 + h) * 512 + s) * 128 + col;
  if (t == 0) qb[off] = val;
  else if (t == 1) kb[off] = val;
  else vT[((size_t)(b * 8 + h) * 128 + col) * 512 + s] = val;
}

// ---------------------------------------------------------------------------
// K5: FUSED scores + softmax + (attn@v + a@rel) -> ctx.
// Swapped QK: C[k][q] (A=K rows, B=Q rows) so each thread holds 4 consecutive
// k per q-column: float4 attn stores, packed LDS attn writes.
// LDS (81,920 B, phase-overlaid, 2 blocks/CU):
//   phase A: As 64x136 | Bs 512x32 | Ps 64x84 f32 | cmask 512 f32 | abufT 64x64
//   phase B: attnb 64x512 (rot64) @0 | Bs2 128x32 / red 4x[4][64] @65536 |
//            abufT @73728 (persists from A)
// ---------------------------------------------------------------------------
__global__ __launch_bounds__(256, 2) void scores_av_fused(
    const unsigned short* __restrict__ qbuf, const unsigned short* __restrict__ kbuf,
    const unsigned short* __restrict__ relb, const unsigned short* __restrict__ vT,
    const unsigned short* __restrict__ relT, const float* __restrict__ relf,
    const int* __restrict__ mask, float* __restrict__ attn_out,
    unsigned short* __restrict__ ctx) {
  __shared__ __align__(16) char smem[81920];
  unsigned short* As = (unsigned short*)smem;                 // 17408 B
  unsigned short* Bs = (unsigned short*)(smem + 17408);       // 32768 B
  float* Ps = (float*)(smem + 50176);                         // 21504 B (64x84)
  float* cmaskS = (float*)(smem + 71680);                     // 2048 B
  unsigned short* abufT = (unsigned short*)(smem + 73728);    // 8192 B (64x64 rot8)
  unsigned short* attnb = (unsigned short*)smem;              // 65536 B (64x512 rot64)
  unsigned short* Bs2 = (unsigned short*)(smem + 65536);      // 8192 B
  float* redb = (float*)(smem + 65536);                       // softmax reduce bufs

  const int idx = blockIdx.x;
  const int qt = idx & 7, bh = idx >> 3, b = bh >> 3;
  const int q0 = qt * 64;
  const size_t qrow0 = (size_t)bh * 512 + q0;
  const int tid = threadIdx.x;
  const int lane = tid & 63, w = tid >> 6;
  const int lanelo = lane & 15, quad = lane >> 4;
  const int rloc4 = lane >> 2, pch4 = lane & 3;
  const int lch4 = (pch4 - rloc4) & 3;        // rot4 source chunk
  const int pB = (quad + lanelo) & 3;         // rotated phys chunk for reads
  const f32x4 zf = {0.f, 0.f, 0.f, 0.f};

  // ---- stage Q tile, column mask; zero bucket tile ----
  for (int c = tid; c < 1024; c += 256) {
    int r = c >> 4, cc = c & 15;
    *(uint4*)(&As[r * 136 + cc * 8]) = *(const uint4*)(qbuf + (qrow0 + r) * 128 + cc * 8);
  }
  for (int i = tid; i < 512; i += 256) cmaskS[i] = mask[b * 512 + i] ? -1e9f : 0.f;
  for (int i = tid; i < 512; i += 256) *(uint4*)(&abufT[i * 8]) = make_uint4(0, 0, 0, 0);
  __syncthreads();

  // ---- P^T[r][q] = rel[r] . q[q]  (A=rel rows, B=Q rows) ----
  f32x4 pacc[5];
#pragma unroll
  for (int j = 0; j < 5; ++j) pacc[j] = zf;
  for (int ks = 0; ks < 4; ++ks) {
    for (int c = tid; c < 320; c += 256) {
      int r = c >> 2, cc = c & 3;
      uint4 v4 = (r < 65) ? *(const uint4*)(relb + r * 128 + ks * 32 + cc * 8)
                          : make_uint4(0, 0, 0, 0);
      *(uint4*)(&Bs[r * 32 + ((cc + r) & 3) * 8]) = v4;   // rot4 layout
    }
    __syncthreads();
    bf16x8 qf_ = *(const bf16x8*)(&As[(w * 16 + lanelo) * 136 + ks * 32 + quad * 8]);
#pragma unroll
    for (int j = 0; j < 5; ++j) {
      bf16x8 rf_ = *(const bf16x8*)(&Bs[(j * 16 + lanelo) * 32 + pB * 8]);
      pacc[j] = MFMA16(rf_, qf_, pacc[j]);   // A=rel -> C rows=r, cols=q
    }
    __syncthreads();
  }
  // Ps[q][r] fp32, row stride 84 (bank-friendly); float4 packed writes
#pragma unroll
  for (int j = 0; j < 5; ++j)
    *(f32x4*)(&Ps[(w * 16 + lanelo) * 84 + j * 16 + quad * 4]) = pacc[j];

  // ---- QK^T swapped: acc[kf][qf] = C[k][q]; wave w owns k in [w*128,w*128+128) ----
  f32x4 acc[8][4];
#pragma unroll
  for (int kf = 0; kf < 8; ++kf)
#pragma unroll
    for (int nf = 0; nf < 4; ++nf) acc[kf][nf] = zf;
  for (int ks = 0; ks < 4; ++ks) {
#pragma unroll
    for (int qq = 0; qq < 8; ++qq) {     // 32 segments of 16 rows; 8 per wave
      int seg = w * 8 + qq;
      int grow = seg * 16 + rloc4;       // k-row 0..511
      gld16(kbuf + ((size_t)bh * 512 + grow) * 128 + ks * 32 + lch4 * 8,
            &Bs[seg * 512]);
    }
    __syncthreads();
    bf16x8 qfr[4];
#pragma unroll
    for (int nf = 0; nf < 4; ++nf)
      qfr[nf] = *(const bf16x8*)(&As[(nf * 16 + lanelo) * 136 + ks * 32 + quad * 8]);
#pragma unroll
    for (int kf = 0; kf < 8; ++kf) {
      bf16x8 kfr = *(const bf16x8*)(&Bs[((w * 8 + kf) * 16 + lanelo) * 32 + pB * 8]);
#pragma unroll
      for (int nf = 0; nf < 4; ++nf) acc[kf][nf] = MFMA16(kfr, qfr[nf], acc[kf][nf]);
    }
    __syncthreads();
  }

  // ---- score fix (rel bias + mask) + per-q max ----
  const float rscale = 0.08838834764831845f;  // 1/sqrt(128)
  float pmax[4] = {-3e38f, -3e38f, -3e38f, -3e38f};
#pragma unroll
  for (int qf = 0; qf < 4; ++qf) {
    const int q = qf * 16 + lanelo;
    const int qg = q0 + q;
    const float* PsR = &Ps[q * 84];
#pragma unroll
    for (int kf = 0; kf < 8; ++kf) {
      const int kbase = w * 128 + kf * 16 + quad * 4;
#pragma unroll
      for (int i = 0; i < 4; ++i) {
        int k = kbase + i;
        int d = k - qg;
        int r = min(max(d, -32), 32) + 32;
        float val = (acc[kf][qf][i] + PsR[r]) * rscale + cmaskS[k];
        acc[kf][qf][i] = val;
        pmax[qf] = fmaxf(pmax[qf], val);
      }
    }
  }
  float* red_max = redb;            // [4][64]
  float* red_sum = redb + 256;
  float* red_s0 = redb + 512;
  float* red_s64 = redb + 768;
#pragma unroll
  for (int qf = 0; qf < 4; ++qf) {
    pmax[qf] = fmaxf(pmax[qf], __shfl_xor(pmax[qf], 16, 64));
    pmax[qf] = fmaxf(pmax[qf], __shfl_xor(pmax[qf], 32, 64));
  }
  if (quad == 0) {
#pragma unroll
    for (int qf = 0; qf < 4; ++qf) red_max[w * 64 + qf * 16 + lanelo] = pmax[qf];
  }
  __syncthreads();
  float mf_[4], psum[4];
#pragma unroll
  for (int qf = 0; qf < 4; ++qf) {
    int q = qf * 16 + lanelo;
    mf_[qf] = fmaxf(fmaxf(red_max[q], red_max[64 + q]),
                    fmaxf(red_max[128 + q], red_max[192 + q]));
    psum[qf] = 0.f;
  }
#pragma unroll
  for (int qf = 0; qf < 4; ++qf)
#pragma unroll
    for (int kf = 0; kf < 8; ++kf)
#pragma unroll
      for (int i = 0; i < 4; ++i) {
        float e = __expf(acc[kf][qf][i] - mf_[qf]);
        acc[kf][qf][i] = e;
        psum[qf] += e;
      }
#pragma unroll
  for (int qf = 0; qf < 4; ++qf) {
    psum[qf] += __shfl_xor(psum[qf], 16, 64);
    psum[qf] += __shfl_xor(psum[qf], 32, 64);
  }
  if (quad == 0) {
#pragma unroll
    for (int qf = 0; qf < 4; ++qf) red_sum[w * 64 + qf * 16 + lanelo] = psum[qf];
  }
  __syncthreads();
  float rs[4];
#pragma unroll
  for (int qf = 0; qf < 4; ++qf) {
    int q = qf * 16 + lanelo;
    float s = red_sum[q] + red_sum[64 + q] + red_sum[128 + q] + red_sum[192 + q];
    rs[qf] = (s > 0.f) ? 1.f / s : 0.f;
  }

  // ---- normalize: float4 attn stores + packed LDS attn + buckets/diag ----
  float s0p[4] = {0.f, 0.f, 0.f, 0.f}, s64p[4] = {0.f, 0.f, 0.f, 0.f};
#pragma unroll
  for (int qf = 0; qf < 4; ++qf) {
    const int q = qf * 16 + lanelo;
    const int qg = q0 + q;
#pragma unroll
    for (int kf = 0; kf < 8; ++kf) {
      const int kbase = w * 128 + kf * 16 + quad * 4;
      float4 at;
      float* ap = (float*)&at;
#pragma unroll
      for (int i = 0; i < 4; ++i) {
        float v = acc[kf][qf][i] * rs[qf];
        ap[i] = v;
        int d = kbase + i - qg;
        if (d <= -32) s0p[qf] += v;
        else if (d >= 32) s64p[qf] += v;
        else {
          int col = d + 32;   // 1..63
          abufT[q * 64 + (((col >> 3) + q) & 7) * 8 + (col & 7)] = f2bf(v);
        }
      }
      *(float4*)(&attn_out[((size_t)bh * 512 + qg) * 512 + kbase]) = at;
      uint2 pk = pack4(at);
      int cc = kbase >> 3;    // 16B chunk index within row
      *(uint2*)(&attnb[q * 512 + ((cc + q) & 63) * 8 + (quad & 1) * 4]) = pk;
    }
  }
  // bucket sums: reduce over quads then over waves
#pragma unroll
  for (int qf = 0; qf < 4; ++qf) {
    s0p[qf] += __shfl_xor(s0p[qf], 16, 64);
    s0p[qf] += __shfl_xor(s0p[qf], 32, 64);
    s64p[qf] += __shfl_xor(s64p[qf], 16, 64);
    s64p[qf] += __shfl_xor(s64p[qf], 32, 64);
  }
  if (quad == 0) {
#pragma unroll
    for (int qf = 0; qf < 4; ++qf) {
      red_s0[w * 64 + qf * 16 + lanelo] = s0p[qf];
      red_s64[w * 64 + qf * 16 + lanelo] = s64p[qf];
    }
  }
  __syncthreads();
  float s0f[4], s64f[4];
#pragma unroll
  for (int qf = 0; qf < 4; ++qf) {
    int q = qf * 16 + lanelo;
    s0f[qf] = red_s0[q] + red_s0[64 + q] + red_s0[128 + q] + red_s0[192 + q];
    s64f[qf] = red_s64[q] + red_s64[64 + q] + red_s64[128 + q] + red_s64[192 + q];
  }
  __syncthreads();   // red bufs dead; Bs2 staging may begin

  // ---- AV: ctx^T[d][q] = vT@attn + relT@abufT (A=vT/relT rows d, B=attn rows q)
  f32x4 cacc[2][4];
#pragma unroll
  for (int mf = 0; mf < 2; ++mf)
#pragma unroll
    for (int nf = 0; nf < 4; ++nf) cacc[mf][nf] = zf;
  for (int kt = 0; kt < 18; ++kt) {
#pragma unroll
    for (int qq = 0; qq < 2; ++qq) {    // 8 segments of 16 d-rows; 2 per wave
      int seg = w * 2 + qq;
      int grow = seg * 16 + rloc4;      // d-row 0..127
      if (kt < 16)
        gld16(vT + ((size_t)bh * 128 + grow) * 512 + kt * 32 + lch4 * 8, &Bs2[seg * 512]);
      else
        gld16(relT + grow * 96 + (kt - 16) * 32 + lch4 * 8, &Bs2[seg * 512]);
    }
    __syncthreads();
    bf16x8 afr[2], bfr[4];
#pragma unroll
    for (int mf = 0; mf < 2; ++mf)
      afr[mf] = *(const bf16x8*)(&Bs2[((w * 2 + mf) * 16 + lanelo) * 32 + pB * 8]);
    if (kt < 16) {
#pragma unroll
      for (int nf = 0; nf < 4; ++nf) {
        int q = nf * 16 + lanelo;
        bfr[nf] = *(const bf16x8*)(&attnb[q * 512 + ((kt * 4 + quad + q) & 63) * 8]);
      }
    } else {
#pragma unroll
      for (int nf = 0; nf < 4; ++nf) {
        int q = nf * 16 + lanelo;
        bfr[nf] = *(const bf16x8*)(&abufT[q * 64 + (((kt - 16) * 4 + quad + q) & 7) * 8]);
      }
    }
#pragma unroll
    for (int mf = 0; mf < 2; ++mf)
#pragma unroll
      for (int nf = 0; nf < 4; ++nf) cacc[mf][nf] = MFMA16(afr[mf], bfr[nf], cacc[mf][nf]);
    __syncthreads();
  }

  // ---- epilogue: + s0*rel[0] + s64*rel[64] (fp32), packed bf16 ctx store ----
  float r0v[2][4], r64v[2][4];
#pragma unroll
  for (int mf = 0; mf < 2; ++mf)
#pragma unroll
    for (int i = 0; i < 4; ++i) {
      int d = w * 32 + mf * 16 + quad * 4 + i;
      r0v[mf][i] = relf[d];
      r64v[mf][i] = relf[64 * 128 + d];
    }
  const int b_ = bh >> 3, h_ = bh & 7;
#pragma unroll
  for (int nf = 0; nf < 4; ++nf) {
    int qg = q0 + nf * 16 + lanelo;
#pragma unroll
    for (int mf = 0; mf < 2; ++mf) {
      unsigned short ov[4];
#pragma unroll
      for (int i = 0; i < 4; ++i) {
        float val = cacc[mf][nf][i] + s0f[nf] * r0v[mf][i] + s64f[nf] * r64v[mf][i];
        ov[i] = f2bf(val);
      }
      uint2 pk;
      pk.x = (unsigned)ov[0] | ((unsigned)ov[1] << 16);
      pk.y = (unsigned)ov[2] | ((unsigned)ov[3] << 16);
      *(uint2*)(&ctx[((size_t)(b_ * 512 + qg)) * 1024 + h_ * 128 + w * 32 + mf * 16 + quad * 4]) = pk;
    }
  }
}

// ---------------------------------------------------------------------------
// K7: out = ctx @ Wo^T + bo. 128x128 tiles; ctx via DMA, Wo fp32->bf16 manual
// staging (rot8 swizzle preserved).
// ---------------------------------------------------------------------------
__global__ __launch_bounds__(256) void out_proj(
    const unsigned short* __restrict__ ctx, const float* __restrict__ Wo,
    const float* __restrict__ bo, float* __restrict__ outp) {
  __shared__ __align__(16) unsigned short As[128 * 64];
  __shared__ __align__(16) unsigned short Bs[128 * 64];
  const int bm = blockIdx.x & 31, bn = blockIdx.x >> 5;
  const int tid = threadIdx.x, lane = tid & 63, w = tid >> 6;
  const int wm = (w >> 1) * 64, wn = (w & 1) * 64;
  const int lanelo = lane & 15, quad = lane >> 4;
  const int row0 = bm * 128, col0 = bn * 128;
  const int rloc = lane >> 3, pch = lane & 7;
  const int lch = (pch - rloc) & 7;
  f32x4 acc[4][4];
  const f32x4 zf = {0.f, 0.f, 0.f, 0.f};
#pragma unroll
  for (int i = 0; i < 4; ++i)
#pragma unroll
    for (int j = 0; j < 4; ++j) acc[i][j] = zf;

  for (int kt = 0; kt < 16; ++kt) {
#pragma unroll
    for (int q = 0; q < 4; ++q) {
      int seg = w * 4 + q;
      int grow = seg * 8 + rloc;
      gld16(ctx + (size_t)(row0 + grow) * 1024 + kt * 64 + lch * 8, &As[seg * 512]);
    }
    for (int c = tid; c < 1024; c += 256) {     // Wo fp32 -> bf16, rot8
      int r = c >> 3, cc2 = c & 7;
      const float* src = Wo + (size_t)(col0 + r) * 1024 + kt * 64 + cc2 * 8;
      int pc = (cc2 + r) & 7;
      *(uint2*)(&Bs[r * 64 + pc * 8]) = pack4(*(const float4*)src);
      *(uint2*)(&Bs[r * 64 + pc * 8 + 4]) = pack4(*(const float4*)(src + 4));
    }
    __syncthreads();
#pragma unroll
    for (int ks = 0; ks < 2; ++ks) {
      const int pA = (ks * 4 + quad + lanelo) & 7;
      bf16x8 a[4], bb[4];
#pragma unroll
      for (int i = 0; i < 4; ++i)
        a[i] = *(const bf16x8*)(&As[(wm + i * 16 + lanelo) * 64 + pA * 8]);
#pragma unroll
      for (int j = 0; j < 4; ++j)
        bb[j] = *(const bf16x8*)(&Bs[(wn + j * 16 + lanelo) * 64 + pA * 8]);
#pragma unroll
      for (int i = 0; i < 4; ++i)
#pragma unroll
        for (int j = 0; j < 4; ++j) acc[i][j] = MFMA16(a[i], bb[j], acc[i][j]);
    }
    __syncthreads();
  }
#pragma unroll
  for (int i = 0; i < 4; ++i) {
#pragma unroll
    for (int j = 0; j < 4; ++j) {
      int n = col0 + wn + j * 16 + lanelo;
      float bbv = bo[n];
#pragma unroll
      for (int r = 0; r < 4; ++r) {
        int m = row0 + wm + i * 16 + quad * 4 + r;
        outp[(size_t)m * 1024 + n] = acc[i][j][r] + bbv;
      }
    }
  }
}

// ---------------------------------------------------------------------------
extern "C" void kernel_launch(void* const* d_in, const int* in_sizes, int n_in,
                              void* d_out, int out_size, void* d_ws, size_t ws_size,
                              hipStream_t stream) {
  const float* x    = (const float*)d_in[0];
  const int*   mask = (const int*)d_in[1];
  const float* Wq   = (const float*)d_in[2];
  const float* bq   = (const float*)d_in[3];
  const float* Wk   = (const float*)d_in[4];
  const float* bk   = (const float*)d_in[5];
  const float* Wv   = (const float*)d_in[6];
  const float* bv   = (const float*)d_in[7];
  const float* Wo   = (const float*)d_in[8];
  const float* bo   = (const float*)d_in[9];
  const float* rel  = (const float*)d_in[10];
  const float* Wihf = (const float*)d_in[11];
  const float* Whhf = (const float*)d_in[12];
  const float* bihf = (const float*)d_in[13];
  const float* bhhf = (const float*)d_in[14];
  const float* Wihb = (const float*)d_in[15];
  const float* Whhb = (const float*)d_in[16];
  const float* bihb = (const float*)d_in[17];
  const float* bhhb = (const float*)d_in[18];

  // ws: 33,595,648 bytes used (proven-safe <= 33,702,144)
  char* ws = (char*)d_ws;
  unsigned short* qb   = (unsigned short*)(ws + 0);          // 8,388,608 B
  unsigned short* kb   = (unsigned short*)(ws + 8388608);    // 8,388,608 B
  unsigned short* vT   = (unsigned short*)(ws + 16777216);   // 8,388,608 B
  unsigned short* ctx  = (unsigned short*)(ws + 25165824);   // 8,388,608 B (own slot: fused kernel writes while other blocks still read qb/kb)
  unsigned short* relb = (unsigned short*)(ws + 33554432);   //    16,640 B
  unsigned short* relT = (unsigned short*)(ws + 33571072);   //    24,576 B

  float* outp  = (float*)d_out;
  float* attnF = outp + 4194304;                 // (B,H,S,S) fp32 = 67.1 MB
  // bf16 scratch inside the attn region; all dead before scores_av_fused
  // overwrites the whole region with fp32 attn:
  unsigned short* abase  = (unsigned short*)attnF;
  unsigned short* xb     = abase;                 // 4,194,304 elems
  unsigned short* vb     = abase + 4194304;       // 4,194,304 elems
  unsigned short* rnnout = abase + 8388608;       // 6,291,456 elems
  unsigned short* Wqkvb  = abase + 14680064;      // 3,145,728 elems
  unsigned short* Wrnnb  = abase + 17825792;      //    65,536 elems

  prep_bf16<<<dim3(7232), dim3(256), 0, stream>>>(
      x, Wq, Wk, Wv, Wihf, Whhf, Wihb, Whhb, xb, Wqkvb, Wrnnb);
  prep_rel<<<dim3(48), dim3(256), 0, stream>>>(rel, relb, relT);
  qkv_proj<<<dim3(768), dim3(256), 0, stream>>>(xb, Wqkvb, bq, bk, bv, mask,
                                                qb, kb, vb, vT);
  rnn_fused<<<dim3(768), dim3(256), 0, stream>>>(qb, kb, vb, Wrnnb,
                                                 bihf, bhhf, bihb, bhhb, rnnout);
  rnn_copyback<<<dim3(24576), dim3(256), 0, stream>>>(rnnout, qb, kb, vT);
  scores_av_fused<<<dim3(512), dim3(256), 0, stream>>>(qb, kb, relb, vT, relT,
                                                       rel, mask, attnF, ctx);
  out_proj<<<dim3(256), dim3(256), 0, stream>>>(ctx, Wo, bo, outp);
}

// Round 2
// 373.127 us; speedup vs baseline: 1.4268x; 1.4268x over previous
//
#include <hip/hip_runtime.h>

// ---------------------------------------------------------------------------
// MultiHeadedAttention w/ n-gram RNN heads + rel-pos embeddings. MFMA version.
// B=8 S=512 D=1024 H=8 DPH=128, MAX_REL=32, NG heads 4..7.
// R11: fused scores+softmax+AV kernel, spill fix. R10's __launch_bounds__(256,2)
// made the backend target higher occupancy and spill the 128-VGPR acc tile to
// scratch (VGPR_Count=128, +39MB sym. FETCH/WRITE excess). Reverted to plain
// __launch_bounds__(256); LDS=81920B already pins 2 blocks/CU.
// Also: block decode bh=idx&63 / qt=idx>>6 so the 8 q-tiles of one bh land on
// ONE XCD (xcd ~= blockIdx%8) -> K/V tiles L2-resident (2.1MB/XCD < 4MB).
//
// ws (33,595,648 B): qb | kb | vT | ctx | relb | relT.
// d_out attn-region scratch (dead before fused kernel overwrites with attn):
//   xb | vb | rnnout | Wqkvb | Wrnnb.
// ---------------------------------------------------------------------------

typedef __bf16 bf16x8 __attribute__((ext_vector_type(8)));
typedef float f32x4 __attribute__((ext_vector_type(4)));

#define MFMA16(a, b, c) __builtin_amdgcn_mfma_f32_16x16x32_bf16(a, b, c, 0, 0, 0)

__device__ __forceinline__ unsigned short f2bf(float f) {
  unsigned u = __float_as_uint(f);
  u += 0x7FFFu + ((u >> 16) & 1u);
  return (unsigned short)(u >> 16);
}
__device__ __forceinline__ uint2 pack4(float4 f) {
  uint2 r;
  r.x = (unsigned)f2bf(f.x) | ((unsigned)f2bf(f.y) << 16);
  r.y = (unsigned)f2bf(f.z) | ((unsigned)f2bf(f.w) << 16);
  return r;
}
// async 16B global->LDS DMA; dest = wave-uniform lds base + lane*16
__device__ __forceinline__ void gld16(const unsigned short* g, unsigned short* l) {
  __builtin_amdgcn_global_load_lds(
      (const __attribute__((address_space(1))) unsigned int*)g,
      (__attribute__((address_space(3))) unsigned int*)l, 16, 0, 0);
}

// ---------------------------------------------------------------------------
// K0: one-shot fp32->bf16 conversion of x, Wq|Wk|Wv, RNN weights.
// (Wo no longer pre-converted: out_proj stages fp32->bf16 on the fly.)
// ---------------------------------------------------------------------------
__global__ __launch_bounds__(256) void prep_bf16(
    const float* __restrict__ x,
    const float* __restrict__ Wq, const float* __restrict__ Wk,
    const float* __restrict__ Wv,
    const float* __restrict__ Wihf, const float* __restrict__ Whhf,
    const float* __restrict__ Wihb, const float* __restrict__ Whhb,
    unsigned short* __restrict__ xb, unsigned short* __restrict__ Wqkvb,
    unsigned short* __restrict__ Wrnnb) {
  int i = blockIdx.x * 256 + threadIdx.x;   // float4 index; grid exact 7232*256
  const float* src;
  unsigned short* dst;
  int off;
  if (i < 1048576) {                    // x
    src = x; dst = xb; off = i;
  } else if (i < 1310720) {             // Wq
    src = Wq; dst = Wqkvb; off = i - 1048576;
  } else if (i < 1572864) {             // Wk
    src = Wk; dst = Wqkvb + 1048576; off = i - 1310720;
  } else if (i < 1835008) {             // Wv
    src = Wv; dst = Wqkvb + 2097152; off = i - 1572864;
  } else if (i < 1839104) {             // Wihf
    src = Wihf; dst = Wrnnb; off = i - 1835008;
  } else if (i < 1843200) {             // Whhf
    src = Whhf; dst = Wrnnb + 16384; off = i - 1839104;
  } else if (i < 1847296) {             // Wihb
    src = Wihb; dst = Wrnnb + 32768; off = i - 1843200;
  } else {                              // Whhb
    src = Whhb; dst = Wrnnb + 49152; off = i - 1847296;
  }
  float4 f = *((const float4*)src + off);
  *(uint2*)(dst + (size_t)off * 4) = pack4(f);
}

// ---------------------------------------------------------------------------
// K1: QKV projection. 128x128 tiles, MFMA, DMA staging w/ rot8 swizzle.
// ---------------------------------------------------------------------------
__global__ __launch_bounds__(256) void qkv_proj(
    const unsigned short* __restrict__ xb, const unsigned short* __restrict__ Wqkvb,
    const float* __restrict__ bq, const float* __restrict__ bk,
    const float* __restrict__ bv, const int* __restrict__ mask,
    unsigned short* __restrict__ qb, unsigned short* __restrict__ kb,
    unsigned short* __restrict__ vb, unsigned short* __restrict__ vT) {
  __shared__ __align__(16) unsigned short As[128 * 64];
  __shared__ __align__(16) unsigned short Bs[128 * 64];
  const int bm = blockIdx.x & 31;
  const int bn = blockIdx.x >> 5;           // 0..23
  const int t = bn >> 3;                    // 0:q 1:k 2:v
  const int nloc0 = (bn & 7) * 128;
  const unsigned short* W = Wqkvb + (size_t)t * 1048576;
  const float* bias = (t == 0) ? bq : (t == 1) ? bk : bv;
  const int tid = threadIdx.x;
  const int lane = tid & 63, w = tid >> 6;
  const int wm = (w >> 1) * 64, wn = (w & 1) * 64;
  const int lanelo = lane & 15, quad = lane >> 4;
  const int row0 = bm * 128;
  const int rloc = lane >> 3, pch = lane & 7;
  const int lch = (pch - rloc) & 7;         // source chunk for rot8 swizzle

  f32x4 acc[4][4];
  const f32x4 zf = {0.f, 0.f, 0.f, 0.f};
#pragma unroll
  for (int i = 0; i < 4; ++i)
#pragma unroll
    for (int j = 0; j < 4; ++j) acc[i][j] = zf;

  for (int kt = 0; kt < 16; ++kt) {
#pragma unroll
    for (int q = 0; q < 4; ++q) {        // 16 segments of 8 rows; 4 per wave
      int seg = w * 4 + q;
      int grow = seg * 8 + rloc;
      gld16(xb + (size_t)(row0 + grow) * 1024 + kt * 64 + lch * 8, &As[seg * 512]);
      gld16(W + (size_t)(nloc0 + grow) * 1024 + kt * 64 + lch * 8, &Bs[seg * 512]);
    }
    __syncthreads();
#pragma unroll
    for (int ks = 0; ks < 2; ++ks) {
      const int pA = (ks * 4 + quad + lanelo) & 7;   // rotated phys chunk
      bf16x8 a[4], bb[4];
#pragma unroll
      for (int i = 0; i < 4; ++i)
        a[i] = *(const bf16x8*)(&As[(wm + i * 16 + lanelo) * 64 + pA * 8]);
#pragma unroll
      for (int j = 0; j < 4; ++j)
        bb[j] = *(const bf16x8*)(&Bs[(wn + j * 16 + lanelo) * 64 + pA * 8]);
#pragma unroll
      for (int i = 0; i < 4; ++i)
#pragma unroll
        for (int j = 0; j < 4; ++j) acc[i][j] = MFMA16(a[i], bb[j], acc[i][j]);
    }
    __syncthreads();
  }
#pragma unroll
  for (int i = 0; i < 4; ++i) {
#pragma unroll
    for (int j = 0; j < 4; ++j) {
      int jj = nloc0 + wn + j * 16 + lanelo;   // 0..1023 within tensor
      int hh = jj >> 7, dc = jj & 127;
      float bvv = bias[jj];
      int m0 = row0 + wm + i * 16 + quad * 4;
      int b0 = m0 >> 9, sS = m0 & 511;
      unsigned short ov[4];
#pragma unroll
      for (int r = 0; r < 4; ++r) {
        int s = sS + r;
        float val = acc[i][j][r] + bvv;
        if (mask[b0 * 512 + s]) val = 0.f;
        unsigned short o = f2bf(val);
        ov[r] = o;
        size_t off = ((size_t)(b0 * 8 + hh) * 512 + s) * 128 + dc;
        if (t == 0) qb[off] = o;
        else if (t == 1) kb[off] = o;
        else vb[off] = o;
      }
      if (t == 2) {
        uint2 pk;
        pk.x = (unsigned)ov[0] | ((unsigned)ov[1] << 16);
        pk.y = (unsigned)ov[2] | ((unsigned)ov[3] << 16);
        *(uint2*)(&vT[((size_t)(b0 * 8 + hh) * 128 + dc) * 512 + sS]) = pk;
      }
    }
  }
}

// ---------------------------------------------------------------------------
// K2: rel prep: relb (65x128 bf16 row-major), relT (128x96 bf16, zero-pad).
// ---------------------------------------------------------------------------
__global__ __launch_bounds__(256) void prep_rel(
    const float* __restrict__ rel, unsigned short* __restrict__ relb,
    unsigned short* __restrict__ relT) {
  int i = blockIdx.x * 256 + threadIdx.x;
  if (i < 65 * 128) relb[i] = f2bf(rel[i]);
  if (i < 128 * 96) {
    int d = i / 96, r = i - d * 96;
    relT[i] = (r < 65) ? f2bf(rel[r * 128 + d]) : (unsigned short)0;
  }
}

// ---------------------------------------------------------------------------
// K3: fused bidirectional 2-step RNN. MFMA. LDS rows padded 128->136.
// ---------------------------------------------------------------------------
__global__ __launch_bounds__(256) void rnn_fused(
    const unsigned short* __restrict__ qb, const unsigned short* __restrict__ kb,
    const unsigned short* __restrict__ vb,
    const unsigned short* __restrict__ Wrnnb,
    const float* __restrict__ bihf, const float* __restrict__ bhhf,
    const float* __restrict__ bihb, const float* __restrict__ bhhb,
    unsigned short* __restrict__ rnn_out) {
  __shared__ __align__(16) unsigned short X[65 * 136];   // rows s0-1 .. s0+63
  __shared__ __align__(16) unsigned short Wi[128 * 136];
  __shared__ __align__(16) unsigned short Wh[128 * 136];
  __shared__ __align__(16) unsigned short H1[64 * 136];
  __shared__ float cbf[128], cbb[128];

  const unsigned short* Wihfb = Wrnnb;
  const unsigned short* Whhfb = Wrnnb + 16384;
  const unsigned short* Wihbb = Wrnnb + 32768;
  const unsigned short* Whhbb = Wrnnb + 49152;

  const int gid = blockIdx.x;
  const int tile = gid & 7;
  const int g = gid >> 3;              // 0..95
  const int t = g >> 5;
  const int rem = g & 31;
  const int b = rem >> 2, h = (rem & 3) + 4;
  const int s0 = tile * 64;
  const unsigned short* src = (t == 0) ? qb : (t == 1) ? kb : vb;
  const size_t rowbase = (size_t)(b * 8 + h) * 512;
  const int tid = threadIdx.x;

  for (int c = tid; c < 65 * 16; c += 256) {   // X: 65 rows x 16 chunks
    int r = c >> 4, cc = c & 15;
    uint4 v4;
    if (r == 0 && s0 == 0) v4 = make_uint4(0, 0, 0, 0);
    else v4 = *(const uint4*)(src + (rowbase + (s0 - 1 + r)) * 128 + cc * 8);
    *(uint4*)(&X[r * 136 + cc * 8]) = v4;
  }
#pragma unroll
  for (int p = 0; p < 8; ++p) {       // weights: 2048 chunks of 8 bf16 each
    int c = p * 256 + tid;
    int r = c >> 4, cc = c & 15;
    *(uint4*)(&Wi[r * 136 + cc * 8]) = *(const uint4*)(Wihfb + c * 8);
    *(uint4*)(&Wh[r * 136 + cc * 8]) = *(const uint4*)(Whhfb + c * 8);
  }
  if (tid < 128) {
    cbf[tid] = bihf[tid] + bhhf[tid];
    cbb[tid] = bihb[tid] + bhhb[tid];
  }
  __syncthreads();

  const int lane = tid & 63, w = tid >> 6;
  const int lanelo = lane & 15, quad = lane >> 4;
  const int marow = w * 16 + lanelo;
  const f32x4 zf = {0.f, 0.f, 0.f, 0.f};

  // ---- forward h1 = tanh(Wihf x_{s-1} + cbf) ----
  f32x4 g1[8];
#pragma unroll
  for (int j = 0; j < 8; ++j) g1[j] = zf;
#pragma unroll
  for (int ks = 0; ks < 4; ++ks) {
    bf16x8 a = *(const bf16x8*)(&X[marow * 136 + ks * 32 + quad * 8]);
#pragma unroll
    for (int j = 0; j < 8; ++j) {
      bf16x8 bb = *(const bf16x8*)(&Wi[(j * 16 + lanelo) * 136 + ks * 32 + quad * 8]);
      g1[j] = MFMA16(a, bb, g1[j]);
    }
  }
#pragma unroll
  for (int j = 0; j < 8; ++j) {
    int col = j * 16 + lanelo;
    float cb = cbf[col];
#pragma unroll
    for (int i = 0; i < 4; ++i) {
      int row = w * 16 + quad * 4 + i;
      H1[row * 136 + col] = f2bf(tanhf(g1[j][i] + cb));
    }
  }
  __syncthreads();
  // ---- forward out = tanh(Wihf x_s + Whhf h1 + cbf) ----
  f32x4 a2[8];
#pragma unroll
  for (int j = 0; j < 8; ++j) a2[j] = zf;
#pragma unroll
  for (int ks = 0; ks < 4; ++ks) {
    bf16x8 a = *(const bf16x8*)(&X[(marow + 1) * 136 + ks * 32 + quad * 8]);
#pragma unroll
    for (int j = 0; j < 8; ++j) {
      bf16x8 bb = *(const bf16x8*)(&Wi[(j * 16 + lanelo) * 136 + ks * 32 + quad * 8]);
      a2[j] = MFMA16(a, bb, a2[j]);
    }
  }
#pragma unroll
  for (int ks = 0; ks < 4; ++ks) {
    bf16x8 a = *(const bf16x8*)(&H1[marow * 136 + ks * 32 + quad * 8]);
#pragma unroll
    for (int j = 0; j < 8; ++j) {
      bf16x8 bb = *(const bf16x8*)(&Wh[(j * 16 + lanelo) * 136 + ks * 32 + quad * 8]);
      a2[j] = MFMA16(a, bb, a2[j]);
    }
  }
  float outF[8][4];
#pragma unroll
  for (int j = 0; j < 8; ++j) {
    int col = j * 16 + lanelo;
    float cb = cbf[col];
#pragma unroll
    for (int i = 0; i < 4; ++i) outF[j][i] = tanhf(a2[j][i] + cb);
  }
  __syncthreads();
#pragma unroll
  for (int p = 0; p < 8; ++p) {   // restage backward weights
    int c = p * 256 + tid;
    int r = c >> 4, cc = c & 15;
    *(uint4*)(&Wi[r * 136 + cc * 8]) = *(const uint4*)(Wihbb + c * 8);
    *(uint4*)(&Wh[r * 136 + cc * 8]) = *(const uint4*)(Whhbb + c * 8);
  }
  __syncthreads();
  // ---- backward h1b = tanh(Wihb x_s + cbb) ----
#pragma unroll
  for (int j = 0; j < 8; ++j) g1[j] = zf;
#pragma unroll
  for (int ks = 0; ks < 4; ++ks) {
    bf16x8 a = *(const bf16x8*)(&X[(marow + 1) * 136 + ks * 32 + quad * 8]);
#pragma unroll
    for (int j = 0; j < 8; ++j) {
      bf16x8 bb = *(const bf16x8*)(&Wi[(j * 16 + lanelo) * 136 + ks * 32 + quad * 8]);
      g1[j] = MFMA16(a, bb, g1[j]);
    }
  }
#pragma unroll
  for (int j = 0; j < 8; ++j) {
    int col = j * 16 + lanelo;
    float cb = cbb[col];
#pragma unroll
    for (int i = 0; i < 4; ++i) {
      int row = w * 16 + quad * 4 + i;
      H1[row * 136 + col] = f2bf(tanhf(g1[j][i] + cb));
    }
  }
  __syncthreads();
  // ---- backward out + combine + store ----
#pragma unroll
  for (int j = 0; j < 8; ++j) a2[j] = zf;
#pragma unroll
  for (int ks = 0; ks < 4; ++ks) {
    bf16x8 a = *(const bf16x8*)(&X[marow * 136 + ks * 32 + quad * 8]);
#pragma unroll
    for (int j = 0; j < 8; ++j) {
      bf16x8 bb = *(const bf16x8*)(&Wi[(j * 16 + lanelo) * 136 + ks * 32 + quad * 8]);
      a2[j] = MFMA16(a, bb, a2[j]);
    }
  }
#pragma unroll
  for (int ks = 0; ks < 4; ++ks) {
    bf16x8 a = *(const bf16x8*)(&H1[marow * 136 + ks * 32 + quad * 8]);
#pragma unroll
    for (int j = 0; j < 8; ++j) {
      bf16x8 bb = *(const bf16x8*)(&Wh[(j * 16 + lanelo) * 136 + ks * 32 + quad * 8]);
      a2[j] = MFMA16(a, bb, a2[j]);
    }
  }
#pragma unroll
  for (int j = 0; j < 8; ++j) {
    int col = j * 16 + lanelo;
    float cb = cbb[col];
#pragma unroll
    for (int i = 0; i < 4; ++i) {
      int row = w * 16 + quad * 4 + i;
      float val = outF[j][i] + tanhf(a2[j][i] + cb);
      rnn_out[((size_t)g * 512 + s0 + row) * 128 + col] = f2bf(val);
    }
  }
}

// ---------------------------------------------------------------------------
// K4: copy rnn results back into qb/kb (+vT for v).
// ---------------------------------------------------------------------------
__global__ __launch_bounds__(256) void rnn_copyback(
    const unsigned short* __restrict__ rnn_out,
    unsigned short* __restrict__ qb, unsigned short* __restrict__ kb,
    unsigned short* __restrict__ vT) {
  int idx = blockIdx.x * 256 + threadIdx.x;   // 6,291,456
  int g = idx >> 16;
  int r2 = idx & 65535;
  int s = r2 >> 7, col = r2 & 127;
  int t = g >> 5, rem = g & 31, b = rem >> 2, h = (rem & 3) + 4;
  unsigned short val = rnn_out[idx];
  size_t off = ((size_t)(b * 8 + h) * 512 + s) * 128 + col;
  if (t == 0) qb[off] = val;
  else if (t == 1) kb[off] = val;
  else vT[((size_t)(b * 8 + h) * 128 + col) * 512 + s] = val;
}

// ---------------------------------------------------------------------------
// K5: FUSED scores + softmax + (attn@v + a@rel) -> ctx.
// Swapped QK: C[k][q] (A=K rows, B=Q rows) so each thread holds 4 consecutive
// k per q-column: float4 attn stores, packed LDS attn writes.
// LDS (81,920 B, phase-overlaid, 2 blocks/CU):
//   phase A: As 64x136 | Bs 512x32 | Ps 64x84 f32 | cmask 512 f32 | abufT 64x64
//   phase B: attnb 64x512 (rot64) @0 | Bs2 128x32 / red 4x[4][64] @65536 |
//            abufT @73728 (persists from A)
// Block decode: bh=idx&63, qt=idx>>6 -> same-bh blocks share an XCD's L2.
// ---------------------------------------------------------------------------
__global__ __launch_bounds__(256) void scores_av_fused(
    const unsigned short* __restrict__ qbuf, const unsigned short* __restrict__ kbuf,
    const unsigned short* __restrict__ relb, const unsigned short* __restrict__ vT,
    const unsigned short* __restrict__ relT, const float* __restrict__ relf,
    const int* __restrict__ mask, float* __restrict__ attn_out,
    unsigned short* __restrict__ ctx) {
  __shared__ __align__(16) char smem[81920];
  unsigned short* As = (unsigned short*)smem;                 // 17408 B
  unsigned short* Bs = (unsigned short*)(smem + 17408);       // 32768 B
  float* Ps = (float*)(smem + 50176);                         // 21504 B (64x84)
  float* cmaskS = (float*)(smem + 71680);                     // 2048 B
  unsigned short* abufT = (unsigned short*)(smem + 73728);    // 8192 B (64x64 rot8)
  unsigned short* attnb = (unsigned short*)smem;              // 65536 B (64x512 rot64)
  unsigned short* Bs2 = (unsigned short*)(smem + 65536);      // 8192 B
  float* redb = (float*)(smem + 65536);                       // softmax reduce bufs

  const int idx = blockIdx.x;
  const int qt = idx >> 6, bh = idx & 63, b = bh >> 3;
  const int q0 = qt * 64;
  const size_t qrow0 = (size_t)bh * 512 + q0;
  const int tid = threadIdx.x;
  const int lane = tid & 63, w = tid >> 6;
  const int lanelo = lane & 15, quad = lane >> 4;
  const int rloc4 = lane >> 2, pch4 = lane & 3;
  const int lch4 = (pch4 - rloc4) & 3;        // rot4 source chunk
  const int pB = (quad + lanelo) & 3;         // rotated phys chunk for reads
  const f32x4 zf = {0.f, 0.f, 0.f, 0.f};

  // ---- stage Q tile, column mask; zero bucket tile ----
  for (int c = tid; c < 1024; c += 256) {
    int r = c >> 4, cc = c & 15;
    *(uint4*)(&As[r * 136 + cc * 8]) = *(const uint4*)(qbuf + (qrow0 + r) * 128 + cc * 8);
  }
  for (int i = tid; i < 512; i += 256) cmaskS[i] = mask[b * 512 + i] ? -1e9f : 0.f;
  for (int i = tid; i < 512; i += 256) *(uint4*)(&abufT[i * 8]) = make_uint4(0, 0, 0, 0);
  __syncthreads();

  // ---- P^T[r][q] = rel[r] . q[q]  (A=rel rows, B=Q rows) ----
  f32x4 pacc[5];
#pragma unroll
  for (int j = 0; j < 5; ++j) pacc[j] = zf;
  for (int ks = 0; ks < 4; ++ks) {
    for (int c = tid; c < 320; c += 256) {
      int r = c >> 2, cc = c & 3;
      uint4 v4 = (r < 65) ? *(const uint4*)(relb + r * 128 + ks * 32 + cc * 8)
                          : make_uint4(0, 0, 0, 0);
      *(uint4*)(&Bs[r * 32 + ((cc + r) & 3) * 8]) = v4;   // rot4 layout
    }
    __syncthreads();
    bf16x8 qf_ = *(const bf16x8*)(&As[(w * 16 + lanelo) * 136 + ks * 32 + quad * 8]);
#pragma unroll
    for (int j = 0; j < 5; ++j) {
      bf16x8 rf_ = *(const bf16x8*)(&Bs[(j * 16 + lanelo) * 32 + pB * 8]);
      pacc[j] = MFMA16(rf_, qf_, pacc[j]);   // A=rel -> C rows=r, cols=q
    }
    __syncthreads();
  }
  // Ps[q][r] fp32, row stride 84 (bank-friendly); float4 packed writes
#pragma unroll
  for (int j = 0; j < 5; ++j)
    *(f32x4*)(&Ps[(w * 16 + lanelo) * 84 + j * 16 + quad * 4]) = pacc[j];

  // ---- QK^T swapped: acc[kf][qf] = C[k][q]; wave w owns k in [w*128,w*128+128) ----
  f32x4 acc[8][4];
#pragma unroll
  for (int kf = 0; kf < 8; ++kf)
#pragma unroll
    for (int nf = 0; nf < 4; ++nf) acc[kf][nf] = zf;
  for (int ks = 0; ks < 4; ++ks) {
#pragma unroll
    for (int qq = 0; qq < 8; ++qq) {     // 32 segments of 16 rows; 8 per wave
      int seg = w * 8 + qq;
      int grow = seg * 16 + rloc4;       // k-row 0..511
      gld16(kbuf + ((size_t)bh * 512 + grow) * 128 + ks * 32 + lch4 * 8,
            &Bs[seg * 512]);
    }
    __syncthreads();
    bf16x8 qfr[4];
#pragma unroll
    for (int nf = 0; nf < 4; ++nf)
      qfr[nf] = *(const bf16x8*)(&As[(nf * 16 + lanelo) * 136 + ks * 32 + quad * 8]);
#pragma unroll
    for (int kf = 0; kf < 8; ++kf) {
      bf16x8 kfr = *(const bf16x8*)(&Bs[((w * 8 + kf) * 16 + lanelo) * 32 + pB * 8]);
#pragma unroll
      for (int nf = 0; nf < 4; ++nf) acc[kf][nf] = MFMA16(kfr, qfr[nf], acc[kf][nf]);
    }
    __syncthreads();
  }

  // ---- score fix (rel bias + mask) + per-q max ----
  const float rscale = 0.08838834764831845f;  // 1/sqrt(128)
  float pmax[4] = {-3e38f, -3e38f, -3e38f, -3e38f};
#pragma unroll
  for (int qf = 0; qf < 4; ++qf) {
    const int q = qf * 16 + lanelo;
    const int qg = q0 + q;
    const float* PsR = &Ps[q * 84];
#pragma unroll
    for (int kf = 0; kf < 8; ++kf) {
      const int kbase = w * 128 + kf * 16 + quad * 4;
#pragma unroll
      for (int i = 0; i < 4; ++i) {
        int k = kbase + i;
        int d = k - qg;
        int r = min(max(d, -32), 32) + 32;
        float val = (acc[kf][qf][i] + PsR[r]) * rscale + cmaskS[k];
        acc[kf][qf][i] = val;
        pmax[qf] = fmaxf(pmax[qf], val);
      }
    }
  }
  float* red_max = redb;            // [4][64]
  float* red_sum = redb + 256;
  float* red_s0 = redb + 512;
  float* red_s64 = redb + 768;
#pragma unroll
  for (int qf = 0; qf < 4; ++qf) {
    pmax[qf] = fmaxf(pmax[qf], __shfl_xor(pmax[qf], 16, 64));
    pmax[qf] = fmaxf(pmax[qf], __shfl_xor(pmax[qf], 32, 64));
  }
  if (quad == 0) {
#pragma unroll
    for (int qf = 0; qf < 4; ++qf) red_max[w * 64 + qf * 16 + lanelo] = pmax[qf];
  }
  __syncthreads();
  float mf_[4], psum[4];
#pragma unroll
  for (int qf = 0; qf < 4; ++qf) {
    int q = qf * 16 + lanelo;
    mf_[qf] = fmaxf(fmaxf(red_max[q], red_max[64 + q]),
                    fmaxf(red_max[128 + q], red_max[192 + q]));
    psum[qf] = 0.f;
  }
#pragma unroll
  for (int qf = 0; qf < 4; ++qf)
#pragma unroll
    for (int kf = 0; kf < 8; ++kf)
#pragma unroll
      for (int i = 0; i < 4; ++i) {
        float e = __expf(acc[kf][qf][i] - mf_[qf]);
        acc[kf][qf][i] = e;
        psum[qf] += e;
      }
#pragma unroll
  for (int qf = 0; qf < 4; ++qf) {
    psum[qf] += __shfl_xor(psum[qf], 16, 64);
    psum[qf] += __shfl_xor(psum[qf], 32, 64);
  }
  if (quad == 0) {
#pragma unroll
    for (int qf = 0; qf < 4; ++qf) red_sum[w * 64 + qf * 16 + lanelo] = psum[qf];
  }
  __syncthreads();
  float rs[4];
#pragma unroll
  for (int qf = 0; qf < 4; ++qf) {
    int q = qf * 16 + lanelo;
    float s = red_sum[q] + red_sum[64 + q] + red_sum[128 + q] + red_sum[192 + q];
    rs[qf] = (s > 0.f) ? 1.f / s : 0.f;
  }

  // ---- normalize: float4 attn stores + packed LDS attn + buckets/diag ----
  float s0p[4] = {0.f, 0.f, 0.f, 0.f}, s64p[4] = {0.f, 0.f, 0.f, 0.f};
#pragma unroll
  for (int qf = 0; qf < 4; ++qf) {
    const int q = qf * 16 + lanelo;
    const int qg = q0 + q;
#pragma unroll
    for (int kf = 0; kf < 8; ++kf) {
      const int kbase = w * 128 + kf * 16 + quad * 4;
      float4 at;
      float* ap = (float*)&at;
#pragma unroll
      for (int i = 0; i < 4; ++i) {
        float v = acc[kf][qf][i] * rs[qf];
        ap[i] = v;
        int d = kbase + i - qg;
        if (d <= -32) s0p[qf] += v;
        else if (d >= 32) s64p[qf] += v;
        else {
          int col = d + 32;   // 1..63
          abufT[q * 64 + (((col >> 3) + q) & 7) * 8 + (col & 7)] = f2bf(v);
        }
      }
      *(float4*)(&attn_out[((size_t)bh * 512 + qg) * 512 + kbase]) = at;
      uint2 pk = pack4(at);
      int cc = kbase >> 3;    // 16B chunk index within row
      *(uint2*)(&attnb[q * 512 + ((cc + q) & 63) * 8 + (quad & 1) * 4]) = pk;
    }
  }
  // bucket sums: reduce over quads then over waves
#pragma unroll
  for (int qf = 0; qf < 4; ++qf) {
    s0p[qf] += __shfl_xor(s0p[qf], 16, 64);
    s0p[qf] += __shfl_xor(s0p[qf], 32, 64);
    s64p[qf] += __shfl_xor(s64p[qf], 16, 64);
    s64p[qf] += __shfl_xor(s64p[qf], 32, 64);
  }
  if (quad == 0) {
#pragma unroll
    for (int qf = 0; qf < 4; ++qf) {
      red_s0[w * 64 + qf * 16 + lanelo] = s0p[qf];
      red_s64[w * 64 + qf * 16 + lanelo] = s64p[qf];
    }
  }
  __syncthreads();
  float s0f[4], s64f[4];
#pragma unroll
  for (int qf = 0; qf < 4; ++qf) {
    int q = qf * 16 + lanelo;
    s0f[qf] = red_s0[q] + red_s0[64 + q] + red_s0[128 + q] + red_s0[192 + q];
    s64f[qf] = red_s64[q] + red_s64[64 + q] + red_s64[128 + q] + red_s64[192 + q];
  }
  __syncthreads();   // red bufs dead; Bs2 staging may begin

  // ---- AV: ctx^T[d][q] = vT@attn + relT@abufT (A=vT/relT rows d, B=attn rows q)
  f32x4 cacc[2][4];
#pragma unroll
  for (int mf = 0; mf < 2; ++mf)
#pragma unroll
    for (int nf = 0; nf < 4; ++nf) cacc[mf][nf] = zf;
  for (int kt = 0; kt < 18; ++kt) {
#pragma unroll
    for (int qq = 0; qq < 2; ++qq) {    // 8 segments of 16 d-rows; 2 per wave
      int seg = w * 2 + qq;
      int grow = seg * 16 + rloc4;      // d-row 0..127
      if (kt < 16)
        gld16(vT + ((size_t)bh * 128 + grow) * 512 + kt * 32 + lch4 * 8, &Bs2[seg * 512]);
      else
        gld16(relT + grow * 96 + (kt - 16) * 32 + lch4 * 8, &Bs2[seg * 512]);
    }
    __syncthreads();
    bf16x8 afr[2], bfr[4];
#pragma unroll
    for (int mf = 0; mf < 2; ++mf)
      afr[mf] = *(const bf16x8*)(&Bs2[((w * 2 + mf) * 16 + lanelo) * 32 + pB * 8]);
    if (kt < 16) {
#pragma unroll
      for (int nf = 0; nf < 4; ++nf) {
        int q = nf * 16 + lanelo;
        bfr[nf] = *(const bf16x8*)(&attnb[q * 512 + ((kt * 4 + quad + q) & 63) * 8]);
      }
    } else {
#pragma unroll
      for (int nf = 0; nf < 4; ++nf) {
        int q = nf * 16 + lanelo;
        bfr[nf] = *(const bf16x8*)(&abufT[q * 64 + (((kt - 16) * 4 + quad + q) & 7) * 8]);
      }
    }
#pragma unroll
    for (int mf = 0; mf < 2; ++mf)
#pragma unroll
      for (int nf = 0; nf < 4; ++nf) cacc[mf][nf] = MFMA16(afr[mf], bfr[nf], cacc[mf][nf]);
    __syncthreads();
  }

  // ---- epilogue: + s0*rel[0] + s64*rel[64] (fp32), packed bf16 ctx store ----
  float r0v[2][4], r64v[2][4];
#pragma unroll
  for (int mf = 0; mf < 2; ++mf)
#pragma unroll
    for (int i = 0; i < 4; ++i) {
      int d = w * 32 + mf * 16 + quad * 4 + i;
      r0v[mf][i] = relf[d];
      r64v[mf][i] = relf[64 * 128 + d];
    }
  const int b_ = bh >> 3, h_ = bh & 7;
#pragma unroll
  for (int nf = 0; nf < 4; ++nf) {
    int qg = q0 + nf * 16 + lanelo;
#pragma unroll
    for (int mf = 0; mf < 2; ++mf) {
      unsigned short ov[4];
#pragma unroll
      for (int i = 0; i < 4; ++i) {
        float val = cacc[mf][nf][i] + s0f[nf] * r0v[mf][i] + s64f[nf] * r64v[mf][i];
        ov[i] = f2bf(val);
      }
      uint2 pk;
      pk.x = (unsigned)ov[0] | ((unsigned)ov[1] << 16);
      pk.y = (unsigned)ov[2] | ((unsigned)ov[3] << 16);
      *(uint2*)(&ctx[((size_t)(b_ * 512 + qg)) * 1024 + h_ * 128 + w * 32 + mf * 16 + quad * 4]) = pk;
    }
  }
}

// ---------------------------------------------------------------------------
// K7: out = ctx @ Wo^T + bo. 128x128 tiles; ctx via DMA, Wo fp32->bf16 manual
// staging (rot8 swizzle preserved).
// ---------------------------------------------------------------------------
__global__ __launch_bounds__(256) void out_proj(
    const unsigned short* __restrict__ ctx, const float* __restrict__ Wo,
    const float* __restrict__ bo, float* __restrict__ outp) {
  __shared__ __align__(16) unsigned short As[128 * 64];
  __shared__ __align__(16) unsigned short Bs[128 * 64];
  const int bm = blockIdx.x & 31, bn = blockIdx.x >> 5;
  const int tid = threadIdx.x, lane = tid & 63, w = tid >> 6;
  const int wm = (w >> 1) * 64, wn = (w & 1) * 64;
  const int lanelo = lane & 15, quad = lane >> 4;
  const int row0 = bm * 128, col0 = bn * 128;
  const int rloc = lane >> 3, pch = lane & 7;
  const int lch = (pch - rloc) & 7;
  f32x4 acc[4][4];
  const f32x4 zf = {0.f, 0.f, 0.f, 0.f};
#pragma unroll
  for (int i = 0; i < 4; ++i)
#pragma unroll
    for (int j = 0; j < 4; ++j) acc[i][j] = zf;

  for (int kt = 0; kt < 16; ++kt) {
#pragma unroll
    for (int q = 0; q < 4; ++q) {
      int seg = w * 4 + q;
      int grow = seg * 8 + rloc;
      gld16(ctx + (size_t)(row0 + grow) * 1024 + kt * 64 + lch * 8, &As[seg * 512]);
    }
    for (int c = tid; c < 1024; c += 256) {     // Wo fp32 -> bf16, rot8
      int r = c >> 3, cc2 = c & 7;
      const float* src = Wo + (size_t)(col0 + r) * 1024 + kt * 64 + cc2 * 8;
      int pc = (cc2 + r) & 7;
      *(uint2*)(&Bs[r * 64 + pc * 8]) = pack4(*(const float4*)src);
      *(uint2*)(&Bs[r * 64 + pc * 8 + 4]) = pack4(*(const float4*)(src + 4));
    }
    __syncthreads();
#pragma unroll
    for (int ks = 0; ks < 2; ++ks) {
      const int pA = (ks * 4 + quad + lanelo) & 7;
      bf16x8 a[4], bb[4];
#pragma unroll
      for (int i = 0; i < 4; ++i)
        a[i] = *(const bf16x8*)(&As[(wm + i * 16 + lanelo) * 64 + pA * 8]);
#pragma unroll
      for (int j = 0; j < 4; ++j)
        bb[j] = *(const bf16x8*)(&Bs[(wn + j * 16 + lanelo) * 64 + pA * 8]);
#pragma unroll
      for (int i = 0; i < 4; ++i)
#pragma unroll
        for (int j = 0; j < 4; ++j) acc[i][j] = MFMA16(a[i], bb[j], acc[i][j]);
    }
    __syncthreads();
  }
#pragma unroll
  for (int i = 0; i < 4; ++i) {
#pragma unroll
    for (int j = 0; j < 4; ++j) {
      int n = col0 + wn + j * 16 + lanelo;
      float bbv = bo[n];
#pragma unroll
      for (int r = 0; r < 4; ++r) {
        int m = row0 + wm + i * 16 + quad * 4 + r;
        outp[(size_t)m * 1024 + n] = acc[i][j][r] + bbv;
      }
    }
  }
}

// ---------------------------------------------------------------------------
extern "C" void kernel_launch(void* const* d_in, const int* in_sizes, int n_in,
                              void* d_out, int out_size, void* d_ws, size_t ws_size,
                              hipStream_t stream) {
  const float* x    = (const float*)d_in[0];
  const int*   mask = (const int*)d_in[1];
  const float* Wq   = (const float*)d_in[2];
  const float* bq   = (const float*)d_in[3];
  const float* Wk   = (const float*)d_in[4];
  const float* bk   = (const float*)d_in[5];
  const float* Wv   = (const float*)d_in[6];
  const float* bv   = (const float*)d_in[7];
  const float* Wo   = (const float*)d_in[8];
  const float* bo   = (const float*)d_in[9];
  const float* rel  = (const float*)d_in[10];
  const float* Wihf = (const float*)d_in[11];
  const float* Whhf = (const float*)d_in[12];
  const float* bihf = (const float*)d_in[13];
  const float* bhhf = (const float*)d_in[14];
  const float* Wihb = (const float*)d_in[15];
  const float* Whhb = (const float*)d_in[16];
  const float* bihb = (const float*)d_in[17];
  const float* bhhb = (const float*)d_in[18];

  // ws: 33,595,648 bytes used (proven-safe <= 33,702,144)
  char* ws = (char*)d_ws;
  unsigned short* qb   = (unsigned short*)(ws + 0);          // 8,388,608 B
  unsigned short* kb   = (unsigned short*)(ws + 8388608);    // 8,388,608 B
  unsigned short* vT   = (unsigned short*)(ws + 16777216);   // 8,388,608 B
  unsigned short* ctx  = (unsigned short*)(ws + 25165824);   // 8,388,608 B
  unsigned short* relb = (unsigned short*)(ws + 33554432);   //    16,640 B
  unsigned short* relT = (unsigned short*)(ws + 33571072);   //    24,576 B

  float* outp  = (float*)d_out;
  float* attnF = outp + 4194304;                 // (B,H,S,S) fp32 = 67.1 MB
  // bf16 scratch inside the attn region; all dead before scores_av_fused
  // overwrites the whole region with fp32 attn:
  unsigned short* abase  = (unsigned short*)attnF;
  unsigned short* xb     = abase;                 // 4,194,304 elems
  unsigned short* vb     = abase + 4194304;       // 4,194,304 elems
  unsigned short* rnnout = abase + 8388608;       // 6,291,456 elems
  unsigned short* Wqkvb  = abase + 14680064;      // 3,145,728 elems
  unsigned short* Wrnnb  = abase + 17825792;      //    65,536 elems

  prep_bf16<<<dim3(7232), dim3(256), 0, stream>>>(
      x, Wq, Wk, Wv, Wihf, Whhf, Wihb, Whhb, xb, Wqkvb, Wrnnb);
  prep_rel<<<dim3(48), dim3(256), 0, stream>>>(rel, relb, relT);
  qkv_proj<<<dim3(768), dim3(256), 0, stream>>>(xb, Wqkvb, bq, bk, bv, mask,
                                                qb, kb, vb, vT);
  rnn_fused<<<dim3(768), dim3(256), 0, stream>>>(qb, kb, vb, Wrnnb,
                                                 bihf, bhhf, bihb, bhhb, rnnout);
  rnn_copyback<<<dim3(24576), dim3(256), 0, stream>>>(rnnout, qb, kb, vT);
  scores_av_fused<<<dim3(512), dim3(256), 0, stream>>>(qb, kb, relb, vT, relT,
                                                       rel, mask, attnF, ctx);
  out_proj<<<dim3(256), dim3(256), 0, stream>>>(ctx, Wo, bo, outp);
}

// Round 3
// 364.103 us; speedup vs baseline: 1.4622x; 1.0248x over previous
//
#include <hip/hip_runtime.h>

// ---------------------------------------------------------------------------
// MultiHeadedAttention w/ n-gram RNN heads + rel-pos embeddings. MFMA version.
// B=8 S=512 D=1024 H=8 DPH=128, MAX_REL=32, NG heads 4..7.
// R12: de-barriered fused scores+softmax+AV kernel. K/vT/relT/rel operand
// fragments are loaded directly global->register (L2-resident via XCD-grouped
// bh blocks) instead of gld16-DMA + barrier staging: 55 -> 5 syncthreads.
// Score-fix and bucket phases use wave-uniform per-fragment d-range
// classification (broadcast p0/p64 for out-of-band frags) instead of 128
// scalar Ps LDS reads per thread.
//
// ws (33,595,648 B): qb | kb | vT | ctx | relb | relT.
// d_out attn-region scratch (dead before fused kernel overwrites with attn):
//   xb | vb | rnnout | Wqkvb | Wrnnb.
// ---------------------------------------------------------------------------

typedef __bf16 bf16x8 __attribute__((ext_vector_type(8)));
typedef float f32x4 __attribute__((ext_vector_type(4)));

#define MFMA16(a, b, c) __builtin_amdgcn_mfma_f32_16x16x32_bf16(a, b, c, 0, 0, 0)

__device__ __forceinline__ unsigned short f2bf(float f) {
  unsigned u = __float_as_uint(f);
  u += 0x7FFFu + ((u >> 16) & 1u);
  return (unsigned short)(u >> 16);
}
__device__ __forceinline__ uint2 pack4(float4 f) {
  uint2 r;
  r.x = (unsigned)f2bf(f.x) | ((unsigned)f2bf(f.y) << 16);
  r.y = (unsigned)f2bf(f.z) | ((unsigned)f2bf(f.w) << 16);
  return r;
}
// async 16B global->LDS DMA; dest = wave-uniform lds base + lane*16
__device__ __forceinline__ void gld16(const unsigned short* g, unsigned short* l) {
  __builtin_amdgcn_global_load_lds(
      (const __attribute__((address_space(1))) unsigned int*)g,
      (__attribute__((address_space(3))) unsigned int*)l, 16, 0, 0);
}

// ---------------------------------------------------------------------------
// K0: one-shot fp32->bf16 conversion of x, Wq|Wk|Wv, RNN weights.
// ---------------------------------------------------------------------------
__global__ __launch_bounds__(256) void prep_bf16(
    const float* __restrict__ x,
    const float* __restrict__ Wq, const float* __restrict__ Wk,
    const float* __restrict__ Wv,
    const float* __restrict__ Wihf, const float* __restrict__ Whhf,
    const float* __restrict__ Wihb, const float* __restrict__ Whhb,
    unsigned short* __restrict__ xb, unsigned short* __restrict__ Wqkvb,
    unsigned short* __restrict__ Wrnnb) {
  int i = blockIdx.x * 256 + threadIdx.x;   // float4 index; grid exact 7232*256
  const float* src;
  unsigned short* dst;
  int off;
  if (i < 1048576) {                    // x
    src = x; dst = xb; off = i;
  } else if (i < 1310720) {             // Wq
    src = Wq; dst = Wqkvb; off = i - 1048576;
  } else if (i < 1572864) {             // Wk
    src = Wk; dst = Wqkvb + 1048576; off = i - 1310720;
  } else if (i < 1835008) {             // Wv
    src = Wv; dst = Wqkvb + 2097152; off = i - 1572864;
  } else if (i < 1839104) {             // Wihf
    src = Wihf; dst = Wrnnb; off = i - 1835008;
  } else if (i < 1843200) {             // Whhf
    src = Whhf; dst = Wrnnb + 16384; off = i - 1839104;
  } else if (i < 1847296) {             // Wihb
    src = Wihb; dst = Wrnnb + 32768; off = i - 1843200;
  } else {                              // Whhb
    src = Whhb; dst = Wrnnb + 49152; off = i - 1847296;
  }
  float4 f = *((const float4*)src + off);
  *(uint2*)(dst + (size_t)off * 4) = pack4(f);
}

// ---------------------------------------------------------------------------
// K1: QKV projection. 128x128 tiles, MFMA, DMA staging w/ rot8 swizzle.
// ---------------------------------------------------------------------------
__global__ __launch_bounds__(256) void qkv_proj(
    const unsigned short* __restrict__ xb, const unsigned short* __restrict__ Wqkvb,
    const float* __restrict__ bq, const float* __restrict__ bk,
    const float* __restrict__ bv, const int* __restrict__ mask,
    unsigned short* __restrict__ qb, unsigned short* __restrict__ kb,
    unsigned short* __restrict__ vb, unsigned short* __restrict__ vT) {
  __shared__ __align__(16) unsigned short As[128 * 64];
  __shared__ __align__(16) unsigned short Bs[128 * 64];
  const int bm = blockIdx.x & 31;
  const int bn = blockIdx.x >> 5;           // 0..23
  const int t = bn >> 3;                    // 0:q 1:k 2:v
  const int nloc0 = (bn & 7) * 128;
  const unsigned short* W = Wqkvb + (size_t)t * 1048576;
  const float* bias = (t == 0) ? bq : (t == 1) ? bk : bv;
  const int tid = threadIdx.x;
  const int lane = tid & 63, w = tid >> 6;
  const int wm = (w >> 1) * 64, wn = (w & 1) * 64;
  const int lanelo = lane & 15, quad = lane >> 4;
  const int row0 = bm * 128;
  const int rloc = lane >> 3, pch = lane & 7;
  const int lch = (pch - rloc) & 7;         // source chunk for rot8 swizzle

  f32x4 acc[4][4];
  const f32x4 zf = {0.f, 0.f, 0.f, 0.f};
#pragma unroll
  for (int i = 0; i < 4; ++i)
#pragma unroll
    for (int j = 0; j < 4; ++j) acc[i][j] = zf;

  for (int kt = 0; kt < 16; ++kt) {
#pragma unroll
    for (int q = 0; q < 4; ++q) {        // 16 segments of 8 rows; 4 per wave
      int seg = w * 4 + q;
      int grow = seg * 8 + rloc;
      gld16(xb + (size_t)(row0 + grow) * 1024 + kt * 64 + lch * 8, &As[seg * 512]);
      gld16(W + (size_t)(nloc0 + grow) * 1024 + kt * 64 + lch * 8, &Bs[seg * 512]);
    }
    __syncthreads();
#pragma unroll
    for (int ks = 0; ks < 2; ++ks) {
      const int pA = (ks * 4 + quad + lanelo) & 7;   // rotated phys chunk
      bf16x8 a[4], bb[4];
#pragma unroll
      for (int i = 0; i < 4; ++i)
        a[i] = *(const bf16x8*)(&As[(wm + i * 16 + lanelo) * 64 + pA * 8]);
#pragma unroll
      for (int j = 0; j < 4; ++j)
        bb[j] = *(const bf16x8*)(&Bs[(wn + j * 16 + lanelo) * 64 + pA * 8]);
#pragma unroll
      for (int i = 0; i < 4; ++i)
#pragma unroll
        for (int j = 0; j < 4; ++j) acc[i][j] = MFMA16(a[i], bb[j], acc[i][j]);
    }
    __syncthreads();
  }
#pragma unroll
  for (int i = 0; i < 4; ++i) {
#pragma unroll
    for (int j = 0; j < 4; ++j) {
      int jj = nloc0 + wn + j * 16 + lanelo;   // 0..1023 within tensor
      int hh = jj >> 7, dc = jj & 127;
      float bvv = bias[jj];
      int m0 = row0 + wm + i * 16 + quad * 4;
      int b0 = m0 >> 9, sS = m0 & 511;
      unsigned short ov[4];
#pragma unroll
      for (int r = 0; r < 4; ++r) {
        int s = sS + r;
        float val = acc[i][j][r] + bvv;
        if (mask[b0 * 512 + s]) val = 0.f;
        unsigned short o = f2bf(val);
        ov[r] = o;
        size_t off = ((size_t)(b0 * 8 + hh) * 512 + s) * 128 + dc;
        if (t == 0) qb[off] = o;
        else if (t == 1) kb[off] = o;
        else vb[off] = o;
      }
      if (t == 2) {
        uint2 pk;
        pk.x = (unsigned)ov[0] | ((unsigned)ov[1] << 16);
        pk.y = (unsigned)ov[2] | ((unsigned)ov[3] << 16);
        *(uint2*)(&vT[((size_t)(b0 * 8 + hh) * 128 + dc) * 512 + sS]) = pk;
      }
    }
  }
}

// ---------------------------------------------------------------------------
// K2: rel prep: relb (65x128 bf16 row-major), relT (128x96 bf16, zero-pad).
// ---------------------------------------------------------------------------
__global__ __launch_bounds__(256) void prep_rel(
    const float* __restrict__ rel, unsigned short* __restrict__ relb,
    unsigned short* __restrict__ relT) {
  int i = blockIdx.x * 256 + threadIdx.x;
  if (i < 65 * 128) relb[i] = f2bf(rel[i]);
  if (i < 128 * 96) {
    int d = i / 96, r = i - d * 96;
    relT[i] = (r < 65) ? f2bf(rel[r * 128 + d]) : (unsigned short)0;
  }
}

// ---------------------------------------------------------------------------
// K3: fused bidirectional 2-step RNN. MFMA. LDS rows padded 128->136.
// ---------------------------------------------------------------------------
__global__ __launch_bounds__(256) void rnn_fused(
    const unsigned short* __restrict__ qb, const unsigned short* __restrict__ kb,
    const unsigned short* __restrict__ vb,
    const unsigned short* __restrict__ Wrnnb,
    const float* __restrict__ bihf, const float* __restrict__ bhhf,
    const float* __restrict__ bihb, const float* __restrict__ bhhb,
    unsigned short* __restrict__ rnn_out) {
  __shared__ __align__(16) unsigned short X[65 * 136];   // rows s0-1 .. s0+63
  __shared__ __align__(16) unsigned short Wi[128 * 136];
  __shared__ __align__(16) unsigned short Wh[128 * 136];
  __shared__ __align__(16) unsigned short H1[64 * 136];
  __shared__ float cbf[128], cbb[128];

  const unsigned short* Wihfb = Wrnnb;
  const unsigned short* Whhfb = Wrnnb + 16384;
  const unsigned short* Wihbb = Wrnnb + 32768;
  const unsigned short* Whhbb = Wrnnb + 49152;

  const int gid = blockIdx.x;
  const int tile = gid & 7;
  const int g = gid >> 3;              // 0..95
  const int t = g >> 5;
  const int rem = g & 31;
  const int b = rem >> 2, h = (rem & 3) + 4;
  const int s0 = tile * 64;
  const unsigned short* src = (t == 0) ? qb : (t == 1) ? kb : vb;
  const size_t rowbase = (size_t)(b * 8 + h) * 512;
  const int tid = threadIdx.x;

  for (int c = tid; c < 65 * 16; c += 256) {   // X: 65 rows x 16 chunks
    int r = c >> 4, cc = c & 15;
    uint4 v4;
    if (r == 0 && s0 == 0) v4 = make_uint4(0, 0, 0, 0);
    else v4 = *(const uint4*)(src + (rowbase + (s0 - 1 + r)) * 128 + cc * 8);
    *(uint4*)(&X[r * 136 + cc * 8]) = v4;
  }
#pragma unroll
  for (int p = 0; p < 8; ++p) {       // weights: 2048 chunks of 8 bf16 each
    int c = p * 256 + tid;
    int r = c >> 4, cc = c & 15;
    *(uint4*)(&Wi[r * 136 + cc * 8]) = *(const uint4*)(Wihfb + c * 8);
    *(uint4*)(&Wh[r * 136 + cc * 8]) = *(const uint4*)(Whhfb + c * 8);
  }
  if (tid < 128) {
    cbf[tid] = bihf[tid] + bhhf[tid];
    cbb[tid] = bihb[tid] + bhhb[tid];
  }
  __syncthreads();

  const int lane = tid & 63, w = tid >> 6;
  const int lanelo = lane & 15, quad = lane >> 4;
  const int marow = w * 16 + lanelo;
  const f32x4 zf = {0.f, 0.f, 0.f, 0.f};

  // ---- forward h1 = tanh(Wihf x_{s-1} + cbf) ----
  f32x4 g1[8];
#pragma unroll
  for (int j = 0; j < 8; ++j) g1[j] = zf;
#pragma unroll
  for (int ks = 0; ks < 4; ++ks) {
    bf16x8 a = *(const bf16x8*)(&X[marow * 136 + ks * 32 + quad * 8]);
#pragma unroll
    for (int j = 0; j < 8; ++j) {
      bf16x8 bb = *(const bf16x8*)(&Wi[(j * 16 + lanelo) * 136 + ks * 32 + quad * 8]);
      g1[j] = MFMA16(a, bb, g1[j]);
    }
  }
#pragma unroll
  for (int j = 0; j < 8; ++j) {
    int col = j * 16 + lanelo;
    float cb = cbf[col];
#pragma unroll
    for (int i = 0; i < 4; ++i) {
      int row = w * 16 + quad * 4 + i;
      H1[row * 136 + col] = f2bf(tanhf(g1[j][i] + cb));
    }
  }
  __syncthreads();
  // ---- forward out = tanh(Wihf x_s + Whhf h1 + cbf) ----
  f32x4 a2[8];
#pragma unroll
  for (int j = 0; j < 8; ++j) a2[j] = zf;
#pragma unroll
  for (int ks = 0; ks < 4; ++ks) {
    bf16x8 a = *(const bf16x8*)(&X[(marow + 1) * 136 + ks * 32 + quad * 8]);
#pragma unroll
    for (int j = 0; j < 8; ++j) {
      bf16x8 bb = *(const bf16x8*)(&Wi[(j * 16 + lanelo) * 136 + ks * 32 + quad * 8]);
      a2[j] = MFMA16(a, bb, a2[j]);
    }
  }
#pragma unroll
  for (int ks = 0; ks < 4; ++ks) {
    bf16x8 a = *(const bf16x8*)(&H1[marow * 136 + ks * 32 + quad * 8]);
#pragma unroll
    for (int j = 0; j < 8; ++j) {
      bf16x8 bb = *(const bf16x8*)(&Wh[(j * 16 + lanelo) * 136 + ks * 32 + quad * 8]);
      a2[j] = MFMA16(a, bb, a2[j]);
    }
  }
  float outF[8][4];
#pragma unroll
  for (int j = 0; j < 8; ++j) {
    int col = j * 16 + lanelo;
    float cb = cbf[col];
#pragma unroll
    for (int i = 0; i < 4; ++i) outF[j][i] = tanhf(a2[j][i] + cb);
  }
  __syncthreads();
#pragma unroll
  for (int p = 0; p < 8; ++p) {   // restage backward weights
    int c = p * 256 + tid;
    int r = c >> 4, cc = c & 15;
    *(uint4*)(&Wi[r * 136 + cc * 8]) = *(const uint4*)(Wihbb + c * 8);
    *(uint4*)(&Wh[r * 136 + cc * 8]) = *(const uint4*)(Whhbb + c * 8);
  }
  __syncthreads();
  // ---- backward h1b = tanh(Wihb x_s + cbb) ----
#pragma unroll
  for (int j = 0; j < 8; ++j) g1[j] = zf;
#pragma unroll
  for (int ks = 0; ks < 4; ++ks) {
    bf16x8 a = *(const bf16x8*)(&X[(marow + 1) * 136 + ks * 32 + quad * 8]);
#pragma unroll
    for (int j = 0; j < 8; ++j) {
      bf16x8 bb = *(const bf16x8*)(&Wi[(j * 16 + lanelo) * 136 + ks * 32 + quad * 8]);
      g1[j] = MFMA16(a, bb, g1[j]);
    }
  }
#pragma unroll
  for (int j = 0; j < 8; ++j) {
    int col = j * 16 + lanelo;
    float cb = cbb[col];
#pragma unroll
    for (int i = 0; i < 4; ++i) {
      int row = w * 16 + quad * 4 + i;
      H1[row * 136 + col] = f2bf(tanhf(g1[j][i] + cb));
    }
  }
  __syncthreads();
  // ---- backward out + combine + store ----
#pragma unroll
  for (int j = 0; j < 8; ++j) a2[j] = zf;
#pragma unroll
  for (int ks = 0; ks < 4; ++ks) {
    bf16x8 a = *(const bf16x8*)(&X[marow * 136 + ks * 32 + quad * 8]);
#pragma unroll
    for (int j = 0; j < 8; ++j) {
      bf16x8 bb = *(const bf16x8*)(&Wi[(j * 16 + lanelo) * 136 + ks * 32 + quad * 8]);
      a2[j] = MFMA16(a, bb, a2[j]);
    }
  }
#pragma unroll
  for (int ks = 0; ks < 4; ++ks) {
    bf16x8 a = *(const bf16x8*)(&H1[marow * 136 + ks * 32 + quad * 8]);
#pragma unroll
    for (int j = 0; j < 8; ++j) {
      bf16x8 bb = *(const bf16x8*)(&Wh[(j * 16 + lanelo) * 136 + ks * 32 + quad * 8]);
      a2[j] = MFMA16(a, bb, a2[j]);
    }
  }
#pragma unroll
  for (int j = 0; j < 8; ++j) {
    int col = j * 16 + lanelo;
    float cb = cbb[col];
#pragma unroll
    for (int i = 0; i < 4; ++i) {
      int row = w * 16 + quad * 4 + i;
      float val = outF[j][i] + tanhf(a2[j][i] + cb);
      rnn_out[((size_t)g * 512 + s0 + row) * 128 + col] = f2bf(val);
    }
  }
}

// ---------------------------------------------------------------------------
// K4: copy rnn results back into qb/kb (+vT for v).
// ---------------------------------------------------------------------------
__global__ __launch_bounds__(256) void rnn_copyback(
    const unsigned short* __restrict__ rnn_out,
    unsigned short* __restrict__ qb, unsigned short* __restrict__ kb,
    unsigned short* __restrict__ vT) {
  int idx = blockIdx.x * 256 + threadIdx.x;   // 6,291,456
  int g = idx >> 16;
  int r2 = idx & 65535;
  int s = r2 >> 7, col = r2 & 127;
  int t = g >> 5, rem = g & 31, b = rem >> 2, h = (rem & 3) + 4;
  unsigned short val = rnn_out[idx];
  size_t off = ((size_t)(b * 8 + h) * 512 + s) * 128 + col;
  if (t == 0) qb[off] = val;
  else if (t == 1) kb[off] = val;
  else vT[((size_t)(b * 8 + h) * 128 + col) * 512 + s] = val;
}

// ---------------------------------------------------------------------------
// K5: FUSED scores + softmax + (attn@v + a@rel) -> ctx.  De-barriered.
// Swapped QK: C[k][q]. K/vT/relT/rel fragments loaded global->register
// directly (no LDS staging, no per-k-step barriers; 5 syncthreads total).
// LDS (77,824 B, 2 blocks/CU):
//   phase A: As 64x136 @0 | Ps 64x84 f32 @17408 | cmask @38912
//   phase B: attnb 64x512 rot64 @0 (aliases all phase A)
//   persistent: abufT 64x64 rot8 @65536 | redb 4x[4][64] f32 @73728
// Block decode: bh=idx&63, qt=idx>>6 -> same-bh blocks share an XCD's L2.
// ---------------------------------------------------------------------------
__global__ __launch_bounds__(256) void scores_av_fused(
    const unsigned short* __restrict__ qbuf, const unsigned short* __restrict__ kbuf,
    const unsigned short* __restrict__ relb, const unsigned short* __restrict__ vT,
    const unsigned short* __restrict__ relT, const float* __restrict__ relf,
    const int* __restrict__ mask, float* __restrict__ attn_out,
    unsigned short* __restrict__ ctx) {
  __shared__ __align__(16) char smem[77824];
  unsigned short* As = (unsigned short*)smem;                 // 17,408 B
  float* Ps = (float*)(smem + 17408);                         // 21,504 B (64x84)
  float* cmaskS = (float*)(smem + 38912);                     // 2,048 B
  unsigned short* attnb = (unsigned short*)smem;              // 65,536 B (phase B)
  unsigned short* abufT = (unsigned short*)(smem + 65536);    // 8,192 B (64x64 rot8)
  float* redb = (float*)(smem + 73728);                       // 4,096 B

  const int idx = blockIdx.x;
  const int qt = idx >> 6, bh = idx & 63, b = bh >> 3;
  const int q0 = qt * 64;
  const size_t qrow0 = (size_t)bh * 512 + q0;
  const int tid = threadIdx.x;
  const int lane = tid & 63, w = tid >> 6;
  const int lanelo = lane & 15, quad = lane >> 4;
  const f32x4 zf = {0.f, 0.f, 0.f, 0.f};

  // ---- stage Q tile, column mask; zero bucket tile ----
  for (int c = tid; c < 1024; c += 256) {
    int r = c >> 4, cc = c & 15;
    *(uint4*)(&As[r * 136 + cc * 8]) = *(const uint4*)(qbuf + (qrow0 + r) * 128 + cc * 8);
  }
  for (int i = tid; i < 512; i += 256) cmaskS[i] = mask[b * 512 + i] ? -1e9f : 0.f;
  for (int i = tid; i < 512; i += 256) *(uint4*)(&abufT[i * 8]) = make_uint4(0, 0, 0, 0);
  __syncthreads();                                  // sync 1

  // ---- P^T[r][q] = rel[r] . q[q]; rel rows loaded direct from global ----
  f32x4 pacc[5];
#pragma unroll
  for (int j = 0; j < 5; ++j) pacc[j] = zf;
#pragma unroll
  for (int ks = 0; ks < 4; ++ks) {
    bf16x8 qf_ = *(const bf16x8*)(&As[(w * 16 + lanelo) * 136 + ks * 32 + quad * 8]);
#pragma unroll
    for (int j = 0; j < 5; ++j) {
      int r = j * 16 + lanelo;
      uint4 tmp = make_uint4(0, 0, 0, 0);
      if (r < 65) tmp = *(const uint4*)(relb + r * 128 + ks * 32 + quad * 8);
      bf16x8 rf_ = *(bf16x8*)&tmp;
      pacc[j] = MFMA16(rf_, qf_, pacc[j]);   // A=rel -> C rows=r, cols=q
    }
  }
  // Ps[q][r] fp32, row stride 84; float4 packed writes (wave w owns q rows w*16..+15)
#pragma unroll
  for (int j = 0; j < 5; ++j)
    *(f32x4*)(&Ps[(w * 16 + lanelo) * 84 + j * 16 + quad * 4]) = pacc[j];
  __syncthreads();                                  // sync 2 (Ps visible to all waves)

  // ---- QK^T swapped: acc[kf][qf] = C[k][q]; K frags direct from global ----
  f32x4 acc[8][4];
#pragma unroll
  for (int kf = 0; kf < 8; ++kf)
#pragma unroll
    for (int nf = 0; nf < 4; ++nf) acc[kf][nf] = zf;
  const unsigned short* kbp = kbuf + (size_t)bh * 65536;
#pragma unroll
  for (int ks = 0; ks < 4; ++ks) {
    bf16x8 qfr[4];
#pragma unroll
    for (int nf = 0; nf < 4; ++nf)
      qfr[nf] = *(const bf16x8*)(&As[(nf * 16 + lanelo) * 136 + ks * 32 + quad * 8]);
    bf16x8 kfr[8];
#pragma unroll
    for (int kf = 0; kf < 8; ++kf)
      kfr[kf] = *(const bf16x8*)(kbp + (size_t)((w * 8 + kf) * 16 + lanelo) * 128 +
                                 ks * 32 + quad * 8);
#pragma unroll
    for (int kf = 0; kf < 8; ++kf)
#pragma unroll
      for (int nf = 0; nf < 4; ++nf) acc[kf][nf] = MFMA16(kfr[kf], qfr[nf], acc[kf][nf]);
  }

  // ---- score fix (rel bias + mask) + per-q max; wave-uniform frag classify ----
  const float rscale = 0.08838834764831845f;  // 1/sqrt(128)
  float pmax[4] = {-3e38f, -3e38f, -3e38f, -3e38f};
#pragma unroll
  for (int qf = 0; qf < 4; ++qf) {
    const int q = qf * 16 + lanelo;
    const int qg = q0 + q;
    const float* PsR = &Ps[q * 84];
    const float p0 = PsR[0], p64 = PsR[64];
    const int qgmin = q0 + qf * 16;
#pragma unroll
    for (int kf = 0; kf < 8; ++kf) {
      const int kmin = w * 128 + kf * 16;
      const int kbase = kmin + quad * 4;
      if (kmin + 15 - qgmin <= -32) {            // whole frag d <= -32 -> r=0
#pragma unroll
        for (int i = 0; i < 4; ++i) {
          float val = (acc[kf][qf][i] + p0) * rscale + cmaskS[kbase + i];
          acc[kf][qf][i] = val;
          pmax[qf] = fmaxf(pmax[qf], val);
        }
      } else if (kmin - (qgmin + 15) >= 32) {    // whole frag d >= 32 -> r=64
#pragma unroll
        for (int i = 0; i < 4; ++i) {
          float val = (acc[kf][qf][i] + p64) * rscale + cmaskS[kbase + i];
          acc[kf][qf][i] = val;
          pmax[qf] = fmaxf(pmax[qf], val);
        }
      } else {                                   // band frag: per-element lookup
#pragma unroll
        for (int i = 0; i < 4; ++i) {
          int k = kbase + i;
          int d = k - qg;
          int r = min(max(d, -32), 32) + 32;
          float val = (acc[kf][qf][i] + PsR[r]) * rscale + cmaskS[k];
          acc[kf][qf][i] = val;
          pmax[qf] = fmaxf(pmax[qf], val);
        }
      }
    }
  }
  float* red_max = redb;            // [4][64]
  float* red_sum = redb + 256;
  float* red_s0 = redb + 512;
  float* red_s64 = redb + 768;
#pragma unroll
  for (int qf = 0; qf < 4; ++qf) {
    pmax[qf] = fmaxf(pmax[qf], __shfl_xor(pmax[qf], 16, 64));
    pmax[qf] = fmaxf(pmax[qf], __shfl_xor(pmax[qf], 32, 64));
  }
  if (quad == 0) {
#pragma unroll
    for (int qf = 0; qf < 4; ++qf) red_max[w * 64 + qf * 16 + lanelo] = pmax[qf];
  }
  __syncthreads();                                  // sync 3
  float mf_[4], psum[4];
#pragma unroll
  for (int qf = 0; qf < 4; ++qf) {
    int q = qf * 16 + lanelo;
    mf_[qf] = fmaxf(fmaxf(red_max[q], red_max[64 + q]),
                    fmaxf(red_max[128 + q], red_max[192 + q]));
    psum[qf] = 0.f;
  }
#pragma unroll
  for (int qf = 0; qf < 4; ++qf)
#pragma unroll
    for (int kf = 0; kf < 8; ++kf)
#pragma unroll
      for (int i = 0; i < 4; ++i) {
        float e = __expf(acc[kf][qf][i] - mf_[qf]);
        acc[kf][qf][i] = e;
        psum[qf] += e;
      }
#pragma unroll
  for (int qf = 0; qf < 4; ++qf) {
    psum[qf] += __shfl_xor(psum[qf], 16, 64);
    psum[qf] += __shfl_xor(psum[qf], 32, 64);
  }
  if (quad == 0) {
#pragma unroll
    for (int qf = 0; qf < 4; ++qf) red_sum[w * 64 + qf * 16 + lanelo] = psum[qf];
  }
  __syncthreads();                                  // sync 4
  float rs[4];
#pragma unroll
  for (int qf = 0; qf < 4; ++qf) {
    int q = qf * 16 + lanelo;
    float s = red_sum[q] + red_sum[64 + q] + red_sum[128 + q] + red_sum[192 + q];
    rs[qf] = (s > 0.f) ? 1.f / s : 0.f;
  }

  // ---- normalize: float4 attn stores + packed LDS attn + buckets (uniform) ----
  float s0p[4] = {0.f, 0.f, 0.f, 0.f}, s64p[4] = {0.f, 0.f, 0.f, 0.f};
#pragma unroll
  for (int qf = 0; qf < 4; ++qf) {
    const int q = qf * 16 + lanelo;
    const int qg = q0 + q;
    const int qgmin = q0 + qf * 16;
#pragma unroll
    for (int kf = 0; kf < 8; ++kf) {
      const int kmin = w * 128 + kf * 16;
      const int kbase = kmin + quad * 4;
      float4 at;
      float* ap = (float*)&at;
#pragma unroll
      for (int i = 0; i < 4; ++i) ap[i] = acc[kf][qf][i] * rs[qf];
      if (kmin + 15 - qgmin <= -32) {            // whole frag -> s0 bucket
#pragma unroll
        for (int i = 0; i < 4; ++i) s0p[qf] += ap[i];
      } else if (kmin - (qgmin + 15) >= 32) {    // whole frag -> s64 bucket
#pragma unroll
        for (int i = 0; i < 4; ++i) s64p[qf] += ap[i];
      } else {                                   // band frag: per-element
#pragma unroll
        for (int i = 0; i < 4; ++i) {
          int d = kbase + i - qg;
          if (d <= -32) s0p[qf] += ap[i];
          else if (d >= 32) s64p[qf] += ap[i];
          else {
            int col = d + 32;   // 1..63
            abufT[q * 64 + (((col >> 3) + q) & 7) * 8 + (col & 7)] = f2bf(ap[i]);
          }
        }
      }
      *(float4*)(&attn_out[((size_t)bh * 512 + qg) * 512 + kbase]) = at;
      uint2 pk = pack4(at);
      int cc = kbase >> 3;    // 16B chunk index within row
      *(uint2*)(&attnb[q * 512 + ((cc + q) & 63) * 8 + (quad & 1) * 4]) = pk;
    }
  }
  // bucket sums: reduce over quads then over waves
#pragma unroll
  for (int qf = 0; qf < 4; ++qf) {
    s0p[qf] += __shfl_xor(s0p[qf], 16, 64);
    s0p[qf] += __shfl_xor(s0p[qf], 32, 64);
    s64p[qf] += __shfl_xor(s64p[qf], 16, 64);
    s64p[qf] += __shfl_xor(s64p[qf], 32, 64);
  }
  if (quad == 0) {
#pragma unroll
    for (int qf = 0; qf < 4; ++qf) {
      red_s0[w * 64 + qf * 16 + lanelo] = s0p[qf];
      red_s64[w * 64 + qf * 16 + lanelo] = s64p[qf];
    }
  }
  __syncthreads();                                  // sync 5 (attnb/abufT/red ready)
  float s0f[4], s64f[4];
#pragma unroll
  for (int qf = 0; qf < 4; ++qf) {
    int q = qf * 16 + lanelo;
    s0f[qf] = red_s0[q] + red_s0[64 + q] + red_s0[128 + q] + red_s0[192 + q];
    s64f[qf] = red_s64[q] + red_s64[64 + q] + red_s64[128 + q] + red_s64[192 + q];
  }

  // ---- AV: ctx^T[d][q] = vT@attn + relT@abufT; A frags direct from global ----
  f32x4 cacc[2][4];
#pragma unroll
  for (int mf = 0; mf < 2; ++mf)
#pragma unroll
    for (int nf = 0; nf < 4; ++nf) cacc[mf][nf] = zf;
  const unsigned short* vbp = vT + (size_t)bh * 65536;
#pragma unroll
  for (int kt = 0; kt < 16; ++kt) {
    bf16x8 afr[2], bfr[4];
#pragma unroll
    for (int mf = 0; mf < 2; ++mf)
      afr[mf] = *(const bf16x8*)(vbp + (size_t)((w * 2 + mf) * 16 + lanelo) * 512 +
                                 kt * 32 + quad * 8);
#pragma unroll
    for (int nf = 0; nf < 4; ++nf) {
      int q = nf * 16 + lanelo;
      bfr[nf] = *(const bf16x8*)(&attnb[q * 512 + ((kt * 4 + quad + q) & 63) * 8]);
    }
#pragma unroll
    for (int mf = 0; mf < 2; ++mf)
#pragma unroll
      for (int nf = 0; nf < 4; ++nf) cacc[mf][nf] = MFMA16(afr[mf], bfr[nf], cacc[mf][nf]);
  }
#pragma unroll
  for (int kt = 16; kt < 18; ++kt) {
    bf16x8 afr[2], bfr[4];
#pragma unroll
    for (int mf = 0; mf < 2; ++mf)
      afr[mf] = *(const bf16x8*)(relT + ((w * 2 + mf) * 16 + lanelo) * 96 +
                                 (kt - 16) * 32 + quad * 8);
#pragma unroll
    for (int nf = 0; nf < 4; ++nf) {
      int q = nf * 16 + lanelo;
      bfr[nf] = *(const bf16x8*)(&abufT[q * 64 + (((kt - 16) * 4 + quad + q) & 7) * 8]);
    }
#pragma unroll
    for (int mf = 0; mf < 2; ++mf)
#pragma unroll
      for (int nf = 0; nf < 4; ++nf) cacc[mf][nf] = MFMA16(afr[mf], bfr[nf], cacc[mf][nf]);
  }

  // ---- epilogue: + s0*rel[0] + s64*rel[64] (fp32), packed bf16 ctx store ----
  float r0v[2][4], r64v[2][4];
#pragma unroll
  for (int mf = 0; mf < 2; ++mf)
#pragma unroll
    for (int i = 0; i < 4; ++i) {
      int d = w * 32 + mf * 16 + quad * 4 + i;
      r0v[mf][i] = relf[d];
      r64v[mf][i] = relf[64 * 128 + d];
    }
  const int b_ = bh >> 3, h_ = bh & 7;
#pragma unroll
  for (int nf = 0; nf < 4; ++nf) {
    int qg = q0 + nf * 16 + lanelo;
#pragma unroll
    for (int mf = 0; mf < 2; ++mf) {
      unsigned short ov[4];
#pragma unroll
      for (int i = 0; i < 4; ++i) {
        float val = cacc[mf][nf][i] + s0f[nf] * r0v[mf][i] + s64f[nf] * r64v[mf][i];
        ov[i] = f2bf(val);
      }
      uint2 pk;
      pk.x = (unsigned)ov[0] | ((unsigned)ov[1] << 16);
      pk.y = (unsigned)ov[2] | ((unsigned)ov[3] << 16);
      *(uint2*)(&ctx[((size_t)(b_ * 512 + qg)) * 1024 + h_ * 128 + w * 32 + mf * 16 + quad * 4]) = pk;
    }
  }
}

// ---------------------------------------------------------------------------
// K7: out = ctx @ Wo^T + bo. 128x128 tiles; ctx via DMA, Wo fp32->bf16 manual
// staging (rot8 swizzle preserved).
// ---------------------------------------------------------------------------
__global__ __launch_bounds__(256) void out_proj(
    const unsigned short* __restrict__ ctx, const float* __restrict__ Wo,
    const float* __restrict__ bo, float* __restrict__ outp) {
  __shared__ __align__(16) unsigned short As[128 * 64];
  __shared__ __align__(16) unsigned short Bs[128 * 64];
  const int bm = blockIdx.x & 31, bn = blockIdx.x >> 5;
  const int tid = threadIdx.x, lane = tid & 63, w = tid >> 6;
  const int wm = (w >> 1) * 64, wn = (w & 1) * 64;
  const int lanelo = lane & 15, quad = lane >> 4;
  const int row0 = bm * 128, col0 = bn * 128;
  const int rloc = lane >> 3, pch = lane & 7;
  const int lch = (pch - rloc) & 7;
  f32x4 acc[4][4];
  const f32x4 zf = {0.f, 0.f, 0.f, 0.f};
#pragma unroll
  for (int i = 0; i < 4; ++i)
#pragma unroll
    for (int j = 0; j < 4; ++j) acc[i][j] = zf;

  for (int kt = 0; kt < 16; ++kt) {
#pragma unroll
    for (int q = 0; q < 4; ++q) {
      int seg = w * 4 + q;
      int grow = seg * 8 + rloc;
      gld16(ctx + (size_t)(row0 + grow) * 1024 + kt * 64 + lch * 8, &As[seg * 512]);
    }
    for (int c = tid; c < 1024; c += 256) {     // Wo fp32 -> bf16, rot8
      int r = c >> 3, cc2 = c & 7;
      const float* src = Wo + (size_t)(col0 + r) * 1024 + kt * 64 + cc2 * 8;
      int pc = (cc2 + r) & 7;
      *(uint2*)(&Bs[r * 64 + pc * 8]) = pack4(*(const float4*)src);
      *(uint2*)(&Bs[r * 64 + pc * 8 + 4]) = pack4(*(const float4*)(src + 4));
    }
    __syncthreads();
#pragma unroll
    for (int ks = 0; ks < 2; ++ks) {
      const int pA = (ks * 4 + quad + lanelo) & 7;
      bf16x8 a[4], bb[4];
#pragma unroll
      for (int i = 0; i < 4; ++i)
        a[i] = *(const bf16x8*)(&As[(wm + i * 16 + lanelo) * 64 + pA * 8]);
#pragma unroll
      for (int j = 0; j < 4; ++j)
        bb[j] = *(const bf16x8*)(&Bs[(wn + j * 16 + lanelo) * 64 + pA * 8]);
#pragma unroll
      for (int i = 0; i < 4; ++i)
#pragma unroll
        for (int j = 0; j < 4; ++j) acc[i][j] = MFMA16(a[i], bb[j], acc[i][j]);
    }
    __syncthreads();
  }
#pragma unroll
  for (int i = 0; i < 4; ++i) {
#pragma unroll
    for (int j = 0; j < 4; ++j) {
      int n = col0 + wn + j * 16 + lanelo;
      float bbv = bo[n];
#pragma unroll
      for (int r = 0; r < 4; ++r) {
        int m = row0 + wm + i * 16 + quad * 4 + r;
        outp[(size_t)m * 1024 + n] = acc[i][j][r] + bbv;
      }
    }
  }
}

// ---------------------------------------------------------------------------
extern "C" void kernel_launch(void* const* d_in, const int* in_sizes, int n_in,
                              void* d_out, int out_size, void* d_ws, size_t ws_size,
                              hipStream_t stream) {
  const float* x    = (const float*)d_in[0];
  const int*   mask = (const int*)d_in[1];
  const float* Wq   = (const float*)d_in[2];
  const float* bq   = (const float*)d_in[3];
  const float* Wk   = (const float*)d_in[4];
  const float* bk   = (const float*)d_in[5];
  const float* Wv   = (const float*)d_in[6];
  const float* bv   = (const float*)d_in[7];
  const float* Wo   = (const float*)d_in[8];
  const float* bo   = (const float*)d_in[9];
  const float* rel  = (const float*)d_in[10];
  const float* Wihf = (const float*)d_in[11];
  const float* Whhf = (const float*)d_in[12];
  const float* bihf = (const float*)d_in[13];
  const float* bhhf = (const float*)d_in[14];
  const float* Wihb = (const float*)d_in[15];
  const float* Whhb = (const float*)d_in[16];
  const float* bihb = (const float*)d_in[17];
  const float* bhhb = (const float*)d_in[18];

  // ws: 33,595,648 bytes used (proven-safe <= 33,702,144)
  char* ws = (char*)d_ws;
  unsigned short* qb   = (unsigned short*)(ws + 0);          // 8,388,608 B
  unsigned short* kb   = (unsigned short*)(ws + 8388608);    // 8,388,608 B
  unsigned short* vT   = (unsigned short*)(ws + 16777216);   // 8,388,608 B
  unsigned short* ctx  = (unsigned short*)(ws + 25165824);   // 8,388,608 B
  unsigned short* relb = (unsigned short*)(ws + 33554432);   //    16,640 B
  unsigned short* relT = (unsigned short*)(ws + 33571072);   //    24,576 B

  float* outp  = (float*)d_out;
  float* attnF = outp + 4194304;                 // (B,H,S,S) fp32 = 67.1 MB
  // bf16 scratch inside the attn region; all dead before scores_av_fused
  // overwrites the whole region with fp32 attn:
  unsigned short* abase  = (unsigned short*)attnF;
  unsigned short* xb     = abase;                 // 4,194,304 elems
  unsigned short* vb     = abase + 4194304;       // 4,194,304 elems
  unsigned short* rnnout = abase + 8388608;       // 6,291,456 elems
  unsigned short* Wqkvb  = abase + 14680064;      // 3,145,728 elems
  unsigned short* Wrnnb  = abase + 17825792;      //    65,536 elems

  prep_bf16<<<dim3(7232), dim3(256), 0, stream>>>(
      x, Wq, Wk, Wv, Wihf, Whhf, Wihb, Whhb, xb, Wqkvb, Wrnnb);
  prep_rel<<<dim3(48), dim3(256), 0, stream>>>(rel, relb, relT);
  qkv_proj<<<dim3(768), dim3(256), 0, stream>>>(xb, Wqkvb, bq, bk, bv, mask,
                                                qb, kb, vb, vT);
  rnn_fused<<<dim3(768), dim3(256), 0, stream>>>(qb, kb, vb, Wrnnb,
                                                 bihf, bhhf, bihb, bhhb, rnnout);
  rnn_copyback<<<dim3(24576), dim3(256), 0, stream>>>(rnnout, qb, kb, vT);
  scores_av_fused<<<dim3(512), dim3(256), 0, stream>>>(qb, kb, relb, vT, relT,
                                                       rel, mask, attnF, ctx);
  out_proj<<<dim3(256), dim3(256), 0, stream>>>(ctx, Wo, bo, outp);
}

// Round 4
// 359.046 us; speedup vs baseline: 1.4828x; 1.0141x over previous
//
#include <hip/hip_runtime.h>

// ---------------------------------------------------------------------------
// MultiHeadedAttention w/ n-gram RNN heads + rel-pos embeddings. MFMA version.
// B=8 S=512 D=1024 H=8 DPH=128, MAX_REL=32, NG heads 4..7.
// R13: fused kernel q-tile 64->32 for occupancy. R12 was latency-bound at
// 2 blocks/CU (LDS 77.8KB, VGPR 224, Occ 10%). Halving the q-tile: grid
// 512->1024 blocks, acc[8][4]->[8][2], LDS 77824->40960 B -> 3-4 blocks/CU.
// P-phase MFMA runs on waves 0-1 only (32 q rows); everything else identical.
//
// ws (33,595,648 B): qb | kb | vT | ctx | relb | relT.
// d_out attn-region scratch (dead before fused kernel overwrites with attn):
//   xb | vb | rnnout | Wqkvb | Wrnnb.
// ---------------------------------------------------------------------------

typedef __bf16 bf16x8 __attribute__((ext_vector_type(8)));
typedef float f32x4 __attribute__((ext_vector_type(4)));

#define MFMA16(a, b, c) __builtin_amdgcn_mfma_f32_16x16x32_bf16(a, b, c, 0, 0, 0)

__device__ __forceinline__ unsigned short f2bf(float f) {
  unsigned u = __float_as_uint(f);
  u += 0x7FFFu + ((u >> 16) & 1u);
  return (unsigned short)(u >> 16);
}
__device__ __forceinline__ uint2 pack4(float4 f) {
  uint2 r;
  r.x = (unsigned)f2bf(f.x) | ((unsigned)f2bf(f.y) << 16);
  r.y = (unsigned)f2bf(f.z) | ((unsigned)f2bf(f.w) << 16);
  return r;
}
// async 16B global->LDS DMA; dest = wave-uniform lds base + lane*16
__device__ __forceinline__ void gld16(const unsigned short* g, unsigned short* l) {
  __builtin_amdgcn_global_load_lds(
      (const __attribute__((address_space(1))) unsigned int*)g,
      (__attribute__((address_space(3))) unsigned int*)l, 16, 0, 0);
}

// ---------------------------------------------------------------------------
// K0: one-shot fp32->bf16 conversion of x, Wq|Wk|Wv, RNN weights.
// ---------------------------------------------------------------------------
__global__ __launch_bounds__(256) void prep_bf16(
    const float* __restrict__ x,
    const float* __restrict__ Wq, const float* __restrict__ Wk,
    const float* __restrict__ Wv,
    const float* __restrict__ Wihf, const float* __restrict__ Whhf,
    const float* __restrict__ Wihb, const float* __restrict__ Whhb,
    unsigned short* __restrict__ xb, unsigned short* __restrict__ Wqkvb,
    unsigned short* __restrict__ Wrnnb) {
  int i = blockIdx.x * 256 + threadIdx.x;   // float4 index; grid exact 7232*256
  const float* src;
  unsigned short* dst;
  int off;
  if (i < 1048576) {                    // x
    src = x; dst = xb; off = i;
  } else if (i < 1310720) {             // Wq
    src = Wq; dst = Wqkvb; off = i - 1048576;
  } else if (i < 1572864) {             // Wk
    src = Wk; dst = Wqkvb + 1048576; off = i - 1310720;
  } else if (i < 1835008) {             // Wv
    src = Wv; dst = Wqkvb + 2097152; off = i - 1572864;
  } else if (i < 1839104) {             // Wihf
    src = Wihf; dst = Wrnnb; off = i - 1835008;
  } else if (i < 1843200) {             // Whhf
    src = Whhf; dst = Wrnnb + 16384; off = i - 1839104;
  } else if (i < 1847296) {             // Wihb
    src = Wihb; dst = Wrnnb + 32768; off = i - 1843200;
  } else {                              // Whhb
    src = Whhb; dst = Wrnnb + 49152; off = i - 1847296;
  }
  float4 f = *((const float4*)src + off);
  *(uint2*)(dst + (size_t)off * 4) = pack4(f);
}

// ---------------------------------------------------------------------------
// K1: QKV projection. 128x128 tiles, MFMA, DMA staging w/ rot8 swizzle.
// ---------------------------------------------------------------------------
__global__ __launch_bounds__(256) void qkv_proj(
    const unsigned short* __restrict__ xb, const unsigned short* __restrict__ Wqkvb,
    const float* __restrict__ bq, const float* __restrict__ bk,
    const float* __restrict__ bv, const int* __restrict__ mask,
    unsigned short* __restrict__ qb, unsigned short* __restrict__ kb,
    unsigned short* __restrict__ vb, unsigned short* __restrict__ vT) {
  __shared__ __align__(16) unsigned short As[128 * 64];
  __shared__ __align__(16) unsigned short Bs[128 * 64];
  const int bm = blockIdx.x & 31;
  const int bn = blockIdx.x >> 5;           // 0..23
  const int t = bn >> 3;                    // 0:q 1:k 2:v
  const int nloc0 = (bn & 7) * 128;
  const unsigned short* W = Wqkvb + (size_t)t * 1048576;
  const float* bias = (t == 0) ? bq : (t == 1) ? bk : bv;
  const int tid = threadIdx.x;
  const int lane = tid & 63, w = tid >> 6;
  const int wm = (w >> 1) * 64, wn = (w & 1) * 64;
  const int lanelo = lane & 15, quad = lane >> 4;
  const int row0 = bm * 128;
  const int rloc = lane >> 3, pch = lane & 7;
  const int lch = (pch - rloc) & 7;         // source chunk for rot8 swizzle

  f32x4 acc[4][4];
  const f32x4 zf = {0.f, 0.f, 0.f, 0.f};
#pragma unroll
  for (int i = 0; i < 4; ++i)
#pragma unroll
    for (int j = 0; j < 4; ++j) acc[i][j] = zf;

  for (int kt = 0; kt < 16; ++kt) {
#pragma unroll
    for (int q = 0; q < 4; ++q) {        // 16 segments of 8 rows; 4 per wave
      int seg = w * 4 + q;
      int grow = seg * 8 + rloc;
      gld16(xb + (size_t)(row0 + grow) * 1024 + kt * 64 + lch * 8, &As[seg * 512]);
      gld16(W + (size_t)(nloc0 + grow) * 1024 + kt * 64 + lch * 8, &Bs[seg * 512]);
    }
    __syncthreads();
#pragma unroll
    for (int ks = 0; ks < 2; ++ks) {
      const int pA = (ks * 4 + quad + lanelo) & 7;   // rotated phys chunk
      bf16x8 a[4], bb[4];
#pragma unroll
      for (int i = 0; i < 4; ++i)
        a[i] = *(const bf16x8*)(&As[(wm + i * 16 + lanelo) * 64 + pA * 8]);
#pragma unroll
      for (int j = 0; j < 4; ++j)
        bb[j] = *(const bf16x8*)(&Bs[(wn + j * 16 + lanelo) * 64 + pA * 8]);
#pragma unroll
      for (int i = 0; i < 4; ++i)
#pragma unroll
        for (int j = 0; j < 4; ++j) acc[i][j] = MFMA16(a[i], bb[j], acc[i][j]);
    }
    __syncthreads();
  }
#pragma unroll
  for (int i = 0; i < 4; ++i) {
#pragma unroll
    for (int j = 0; j < 4; ++j) {
      int jj = nloc0 + wn + j * 16 + lanelo;   // 0..1023 within tensor
      int hh = jj >> 7, dc = jj & 127;
      float bvv = bias[jj];
      int m0 = row0 + wm + i * 16 + quad * 4;
      int b0 = m0 >> 9, sS = m0 & 511;
      unsigned short ov[4];
#pragma unroll
      for (int r = 0; r < 4; ++r) {
        int s = sS + r;
        float val = acc[i][j][r] + bvv;
        if (mask[b0 * 512 + s]) val = 0.f;
        unsigned short o = f2bf(val);
        ov[r] = o;
        size_t off = ((size_t)(b0 * 8 + hh) * 512 + s) * 128 + dc;
        if (t == 0) qb[off] = o;
        else if (t == 1) kb[off] = o;
        else vb[off] = o;
      }
      if (t == 2) {
        uint2 pk;
        pk.x = (unsigned)ov[0] | ((unsigned)ov[1] << 16);
        pk.y = (unsigned)ov[2] | ((unsigned)ov[3] << 16);
        *(uint2*)(&vT[((size_t)(b0 * 8 + hh) * 128 + dc) * 512 + sS]) = pk;
      }
    }
  }
}

// ---------------------------------------------------------------------------
// K2: rel prep: relb (65x128 bf16 row-major), relT (128x96 bf16, zero-pad).
// ---------------------------------------------------------------------------
__global__ __launch_bounds__(256) void prep_rel(
    const float* __restrict__ rel, unsigned short* __restrict__ relb,
    unsigned short* __restrict__ relT) {
  int i = blockIdx.x * 256 + threadIdx.x;
  if (i < 65 * 128) relb[i] = f2bf(rel[i]);
  if (i < 128 * 96) {
    int d = i / 96, r = i - d * 96;
    relT[i] = (r < 65) ? f2bf(rel[r * 128 + d]) : (unsigned short)0;
  }
}

// ---------------------------------------------------------------------------
// K3: fused bidirectional 2-step RNN. MFMA. LDS rows padded 128->136.
// ---------------------------------------------------------------------------
__global__ __launch_bounds__(256) void rnn_fused(
    const unsigned short* __restrict__ qb, const unsigned short* __restrict__ kb,
    const unsigned short* __restrict__ vb,
    const unsigned short* __restrict__ Wrnnb,
    const float* __restrict__ bihf, const float* __restrict__ bhhf,
    const float* __restrict__ bihb, const float* __restrict__ bhhb,
    unsigned short* __restrict__ rnn_out) {
  __shared__ __align__(16) unsigned short X[65 * 136];   // rows s0-1 .. s0+63
  __shared__ __align__(16) unsigned short Wi[128 * 136];
  __shared__ __align__(16) unsigned short Wh[128 * 136];
  __shared__ __align__(16) unsigned short H1[64 * 136];
  __shared__ float cbf[128], cbb[128];

  const unsigned short* Wihfb = Wrnnb;
  const unsigned short* Whhfb = Wrnnb + 16384;
  const unsigned short* Wihbb = Wrnnb + 32768;
  const unsigned short* Whhbb = Wrnnb + 49152;

  const int gid = blockIdx.x;
  const int tile = gid & 7;
  const int g = gid >> 3;              // 0..95
  const int t = g >> 5;
  const int rem = g & 31;
  const int b = rem >> 2, h = (rem & 3) + 4;
  const int s0 = tile * 64;
  const unsigned short* src = (t == 0) ? qb : (t == 1) ? kb : vb;
  const size_t rowbase = (size_t)(b * 8 + h) * 512;
  const int tid = threadIdx.x;

  for (int c = tid; c < 65 * 16; c += 256) {   // X: 65 rows x 16 chunks
    int r = c >> 4, cc = c & 15;
    uint4 v4;
    if (r == 0 && s0 == 0) v4 = make_uint4(0, 0, 0, 0);
    else v4 = *(const uint4*)(src + (rowbase + (s0 - 1 + r)) * 128 + cc * 8);
    *(uint4*)(&X[r * 136 + cc * 8]) = v4;
  }
#pragma unroll
  for (int p = 0; p < 8; ++p) {       // weights: 2048 chunks of 8 bf16 each
    int c = p * 256 + tid;
    int r = c >> 4, cc = c & 15;
    *(uint4*)(&Wi[r * 136 + cc * 8]) = *(const uint4*)(Wihfb + c * 8);
    *(uint4*)(&Wh[r * 136 + cc * 8]) = *(const uint4*)(Whhfb + c * 8);
  }
  if (tid < 128) {
    cbf[tid] = bihf[tid] + bhhf[tid];
    cbb[tid] = bihb[tid] + bhhb[tid];
  }
  __syncthreads();

  const int lane = tid & 63, w = tid >> 6;
  const int lanelo = lane & 15, quad = lane >> 4;
  const int marow = w * 16 + lanelo;
  const f32x4 zf = {0.f, 0.f, 0.f, 0.f};

  // ---- forward h1 = tanh(Wihf x_{s-1} + cbf) ----
  f32x4 g1[8];
#pragma unroll
  for (int j = 0; j < 8; ++j) g1[j] = zf;
#pragma unroll
  for (int ks = 0; ks < 4; ++ks) {
    bf16x8 a = *(const bf16x8*)(&X[marow * 136 + ks * 32 + quad * 8]);
#pragma unroll
    for (int j = 0; j < 8; ++j) {
      bf16x8 bb = *(const bf16x8*)(&Wi[(j * 16 + lanelo) * 136 + ks * 32 + quad * 8]);
      g1[j] = MFMA16(a, bb, g1[j]);
    }
  }
#pragma unroll
  for (int j = 0; j < 8; ++j) {
    int col = j * 16 + lanelo;
    float cb = cbf[col];
#pragma unroll
    for (int i = 0; i < 4; ++i) {
      int row = w * 16 + quad * 4 + i;
      H1[row * 136 + col] = f2bf(tanhf(g1[j][i] + cb));
    }
  }
  __syncthreads();
  // ---- forward out = tanh(Wihf x_s + Whhf h1 + cbf) ----
  f32x4 a2[8];
#pragma unroll
  for (int j = 0; j < 8; ++j) a2[j] = zf;
#pragma unroll
  for (int ks = 0; ks < 4; ++ks) {
    bf16x8 a = *(const bf16x8*)(&X[(marow + 1) * 136 + ks * 32 + quad * 8]);
#pragma unroll
    for (int j = 0; j < 8; ++j) {
      bf16x8 bb = *(const bf16x8*)(&Wi[(j * 16 + lanelo) * 136 + ks * 32 + quad * 8]);
      a2[j] = MFMA16(a, bb, a2[j]);
    }
  }
#pragma unroll
  for (int ks = 0; ks < 4; ++ks) {
    bf16x8 a = *(const bf16x8*)(&H1[marow * 136 + ks * 32 + quad * 8]);
#pragma unroll
    for (int j = 0; j < 8; ++j) {
      bf16x8 bb = *(const bf16x8*)(&Wh[(j * 16 + lanelo) * 136 + ks * 32 + quad * 8]);
      a2[j] = MFMA16(a, bb, a2[j]);
    }
  }
  float outF[8][4];
#pragma unroll
  for (int j = 0; j < 8; ++j) {
    int col = j * 16 + lanelo;
    float cb = cbf[col];
#pragma unroll
    for (int i = 0; i < 4; ++i) outF[j][i] = tanhf(a2[j][i] + cb);
  }
  __syncthreads();
#pragma unroll
  for (int p = 0; p < 8; ++p) {   // restage backward weights
    int c = p * 256 + tid;
    int r = c >> 4, cc = c & 15;
    *(uint4*)(&Wi[r * 136 + cc * 8]) = *(const uint4*)(Wihbb + c * 8);
    *(uint4*)(&Wh[r * 136 + cc * 8]) = *(const uint4*)(Whhbb + c * 8);
  }
  __syncthreads();
  // ---- backward h1b = tanh(Wihb x_s + cbb) ----
#pragma unroll
  for (int j = 0; j < 8; ++j) g1[j] = zf;
#pragma unroll
  for (int ks = 0; ks < 4; ++ks) {
    bf16x8 a = *(const bf16x8*)(&X[(marow + 1) * 136 + ks * 32 + quad * 8]);
#pragma unroll
    for (int j = 0; j < 8; ++j) {
      bf16x8 bb = *(const bf16x8*)(&Wi[(j * 16 + lanelo) * 136 + ks * 32 + quad * 8]);
      g1[j] = MFMA16(a, bb, g1[j]);
    }
  }
#pragma unroll
  for (int j = 0; j < 8; ++j) {
    int col = j * 16 + lanelo;
    float cb = cbb[col];
#pragma unroll
    for (int i = 0; i < 4; ++i) {
      int row = w * 16 + quad * 4 + i;
      H1[row * 136 + col] = f2bf(tanhf(g1[j][i] + cb));
    }
  }
  __syncthreads();
  // ---- backward out + combine + store ----
#pragma unroll
  for (int j = 0; j < 8; ++j) a2[j] = zf;
#pragma unroll
  for (int ks = 0; ks < 4; ++ks) {
    bf16x8 a = *(const bf16x8*)(&X[marow * 136 + ks * 32 + quad * 8]);
#pragma unroll
    for (int j = 0; j < 8; ++j) {
      bf16x8 bb = *(const bf16x8*)(&Wi[(j * 16 + lanelo) * 136 + ks * 32 + quad * 8]);
      a2[j] = MFMA16(a, bb, a2[j]);
    }
  }
#pragma unroll
  for (int ks = 0; ks < 4; ++ks) {
    bf16x8 a = *(const bf16x8*)(&H1[marow * 136 + ks * 32 + quad * 8]);
#pragma unroll
    for (int j = 0; j < 8; ++j) {
      bf16x8 bb = *(const bf16x8*)(&Wh[(j * 16 + lanelo) * 136 + ks * 32 + quad * 8]);
      a2[j] = MFMA16(a, bb, a2[j]);
    }
  }
#pragma unroll
  for (int j = 0; j < 8; ++j) {
    int col = j * 16 + lanelo;
    float cb = cbb[col];
#pragma unroll
    for (int i = 0; i < 4; ++i) {
      int row = w * 16 + quad * 4 + i;
      float val = outF[j][i] + tanhf(a2[j][i] + cb);
      rnn_out[((size_t)g * 512 + s0 + row) * 128 + col] = f2bf(val);
    }
  }
}

// ---------------------------------------------------------------------------
// K4: copy rnn results back into qb/kb (+vT for v).
// ---------------------------------------------------------------------------
__global__ __launch_bounds__(256) void rnn_copyback(
    const unsigned short* __restrict__ rnn_out,
    unsigned short* __restrict__ qb, unsigned short* __restrict__ kb,
    unsigned short* __restrict__ vT) {
  int idx = blockIdx.x * 256 + threadIdx.x;   // 6,291,456
  int g = idx >> 16;
  int r2 = idx & 65535;
  int s = r2 >> 7, col = r2 & 127;
  int t = g >> 5, rem = g & 31, b = rem >> 2, h = (rem & 3) + 4;
  unsigned short val = rnn_out[idx];
  size_t off = ((size_t)(b * 8 + h) * 512 + s) * 128 + col;
  if (t == 0) qb[off] = val;
  else if (t == 1) kb[off] = val;
  else vT[((size_t)(b * 8 + h) * 128 + col) * 512 + s] = val;
}

// ---------------------------------------------------------------------------
// K5: FUSED scores + softmax + (attn@v + a@rel) -> ctx.  q-tile = 32 rows.
// Swapped QK: C[k][q]. K/vT/relT/rel fragments loaded global->register
// directly; 5 syncthreads total. Grid 1024 = bh(64) x qt(16).
// LDS (40,960 B -> 3-4 blocks/CU):
//   phase A: As 32x136 @0 | Ps 32x84 f32 @8704 | cmask @19456
//   phase B: attnb 32x512 rot64 @0 (aliases all phase A)
//   persistent: abufT 32x64 rot8 @32768 | redb 4x[4 waves][stride64] @36864
// Block decode: bh=idx&63 -> same-bh blocks share an XCD's L2.
// ---------------------------------------------------------------------------
__global__ __launch_bounds__(256) void scores_av_fused(
    const unsigned short* __restrict__ qbuf, const unsigned short* __restrict__ kbuf,
    const unsigned short* __restrict__ relb, const unsigned short* __restrict__ vT,
    const unsigned short* __restrict__ relT, const float* __restrict__ relf,
    const int* __restrict__ mask, float* __restrict__ attn_out,
    unsigned short* __restrict__ ctx) {
  __shared__ __align__(16) char smem[40960];
  unsigned short* As = (unsigned short*)smem;                 // 8,704 B (32x136)
  float* Ps = (float*)(smem + 8704);                          // 10,752 B (32x84)
  float* cmaskS = (float*)(smem + 19456);                     // 2,048 B
  unsigned short* attnb = (unsigned short*)smem;              // 32,768 B (phase B)
  unsigned short* abufT = (unsigned short*)(smem + 32768);    // 4,096 B (32x64 rot8)
  float* redb = (float*)(smem + 36864);                       // 4,096 B

  const int idx = blockIdx.x;
  const int qt = idx >> 6, bh = idx & 63, b = bh >> 3;
  const int q0 = qt * 32;
  const size_t qrow0 = (size_t)bh * 512 + q0;
  const int tid = threadIdx.x;
  const int lane = tid & 63, w = tid >> 6;
  const int lanelo = lane & 15, quad = lane >> 4;
  const f32x4 zf = {0.f, 0.f, 0.f, 0.f};

  // ---- stage Q tile (32x128), column mask; zero bucket tile ----
  for (int c = tid; c < 512; c += 256) {
    int r = c >> 4, cc = c & 15;
    *(uint4*)(&As[r * 136 + cc * 8]) = *(const uint4*)(qbuf + (qrow0 + r) * 128 + cc * 8);
  }
  for (int i = tid; i < 512; i += 256) cmaskS[i] = mask[b * 512 + i] ? -1e9f : 0.f;
  if (tid < 256) *(uint4*)(&abufT[tid * 8]) = make_uint4(0, 0, 0, 0);
  __syncthreads();                                  // sync 1

  // ---- P^T[r][q] = rel[r] . q[q]; waves 0-1 only (q rows 0-31) ----
  if (w < 2) {
    f32x4 pacc[5];
#pragma unroll
    for (int j = 0; j < 5; ++j) pacc[j] = zf;
#pragma unroll
    for (int ks = 0; ks < 4; ++ks) {
      bf16x8 qf_ = *(const bf16x8*)(&As[(w * 16 + lanelo) * 136 + ks * 32 + quad * 8]);
#pragma unroll
      for (int j = 0; j < 5; ++j) {
        int r = j * 16 + lanelo;
        uint4 tmp = make_uint4(0, 0, 0, 0);
        if (r < 65) tmp = *(const uint4*)(relb + r * 128 + ks * 32 + quad * 8);
        bf16x8 rf_ = *(bf16x8*)&tmp;
        pacc[j] = MFMA16(rf_, qf_, pacc[j]);   // A=rel -> C rows=r, cols=q
      }
    }
    // Ps[q][r] fp32, row stride 84; float4 packed writes
#pragma unroll
    for (int j = 0; j < 5; ++j)
      *(f32x4*)(&Ps[(w * 16 + lanelo) * 84 + j * 16 + quad * 4]) = pacc[j];
  }
  __syncthreads();                                  // sync 2 (Ps visible)

  // ---- QK^T swapped: acc[kf][qf] = C[k][q]; K frags direct from global ----
  f32x4 acc[8][2];
#pragma unroll
  for (int kf = 0; kf < 8; ++kf)
#pragma unroll
    for (int nf = 0; nf < 2; ++nf) acc[kf][nf] = zf;
  const unsigned short* kbp = kbuf + (size_t)bh * 65536;
#pragma unroll
  for (int ks = 0; ks < 4; ++ks) {
    bf16x8 qfr[2];
#pragma unroll
    for (int nf = 0; nf < 2; ++nf)
      qfr[nf] = *(const bf16x8*)(&As[(nf * 16 + lanelo) * 136 + ks * 32 + quad * 8]);
    bf16x8 kfr[8];
#pragma unroll
    for (int kf = 0; kf < 8; ++kf)
      kfr[kf] = *(const bf16x8*)(kbp + (size_t)((w * 8 + kf) * 16 + lanelo) * 128 +
                                 ks * 32 + quad * 8);
#pragma unroll
    for (int kf = 0; kf < 8; ++kf)
#pragma unroll
      for (int nf = 0; nf < 2; ++nf) acc[kf][nf] = MFMA16(kfr[kf], qfr[nf], acc[kf][nf]);
  }

  // ---- score fix (rel bias + mask) + per-q max; wave-uniform frag classify ----
  const float rscale = 0.08838834764831845f;  // 1/sqrt(128)
  float pmax[2] = {-3e38f, -3e38f};
#pragma unroll
  for (int qf = 0; qf < 2; ++qf) {
    const int q = qf * 16 + lanelo;
    const int qg = q0 + q;
    const float* PsR = &Ps[q * 84];
    const float p0 = PsR[0], p64 = PsR[64];
    const int qgmin = q0 + qf * 16;
#pragma unroll
    for (int kf = 0; kf < 8; ++kf) {
      const int kmin = w * 128 + kf * 16;
      const int kbase = kmin + quad * 4;
      if (kmin + 15 - qgmin <= -32) {            // whole frag d <= -32 -> r=0
#pragma unroll
        for (int i = 0; i < 4; ++i) {
          float val = (acc[kf][qf][i] + p0) * rscale + cmaskS[kbase + i];
          acc[kf][qf][i] = val;
          pmax[qf] = fmaxf(pmax[qf], val);
        }
      } else if (kmin - (qgmin + 15) >= 32) {    // whole frag d >= 32 -> r=64
#pragma unroll
        for (int i = 0; i < 4; ++i) {
          float val = (acc[kf][qf][i] + p64) * rscale + cmaskS[kbase + i];
          acc[kf][qf][i] = val;
          pmax[qf] = fmaxf(pmax[qf], val);
        }
      } else {                                   // band frag: per-element lookup
#pragma unroll
        for (int i = 0; i < 4; ++i) {
          int k = kbase + i;
          int d = k - qg;
          int r = min(max(d, -32), 32) + 32;
          float val = (acc[kf][qf][i] + PsR[r]) * rscale + cmaskS[k];
          acc[kf][qf][i] = val;
          pmax[qf] = fmaxf(pmax[qf], val);
        }
      }
    }
  }
  float* red_max = redb;            // stride-64 rows per wave
  float* red_sum = redb + 256;
  float* red_s0 = redb + 512;
  float* red_s64 = redb + 768;
#pragma unroll
  for (int qf = 0; qf < 2; ++qf) {
    pmax[qf] = fmaxf(pmax[qf], __shfl_xor(pmax[qf], 16, 64));
    pmax[qf] = fmaxf(pmax[qf], __shfl_xor(pmax[qf], 32, 64));
  }
  if (quad == 0) {
#pragma unroll
    for (int qf = 0; qf < 2; ++qf) red_max[w * 64 + qf * 16 + lanelo] = pmax[qf];
  }
  __syncthreads();                                  // sync 3
  float mf_[2], psum[2];
#pragma unroll
  for (int qf = 0; qf < 2; ++qf) {
    int q = qf * 16 + lanelo;
    mf_[qf] = fmaxf(fmaxf(red_max[q], red_max[64 + q]),
                    fmaxf(red_max[128 + q], red_max[192 + q]));
    psum[qf] = 0.f;
  }
#pragma unroll
  for (int qf = 0; qf < 2; ++qf)
#pragma unroll
    for (int kf = 0; kf < 8; ++kf)
#pragma unroll
      for (int i = 0; i < 4; ++i) {
        float e = __expf(acc[kf][qf][i] - mf_[qf]);
        acc[kf][qf][i] = e;
        psum[qf] += e;
      }
#pragma unroll
  for (int qf = 0; qf < 2; ++qf) {
    psum[qf] += __shfl_xor(psum[qf], 16, 64);
    psum[qf] += __shfl_xor(psum[qf], 32, 64);
  }
  if (quad == 0) {
#pragma unroll
    for (int qf = 0; qf < 2; ++qf) red_sum[w * 64 + qf * 16 + lanelo] = psum[qf];
  }
  __syncthreads();                                  // sync 4
  float rs[2];
#pragma unroll
  for (int qf = 0; qf < 2; ++qf) {
    int q = qf * 16 + lanelo;
    float s = red_sum[q] + red_sum[64 + q] + red_sum[128 + q] + red_sum[192 + q];
    rs[qf] = (s > 0.f) ? 1.f / s : 0.f;
  }

  // ---- normalize: float4 attn stores + packed LDS attn + buckets (uniform) ----
  float s0p[2] = {0.f, 0.f}, s64p[2] = {0.f, 0.f};
#pragma unroll
  for (int qf = 0; qf < 2; ++qf) {
    const int q = qf * 16 + lanelo;
    const int qg = q0 + q;
    const int qgmin = q0 + qf * 16;
#pragma unroll
    for (int kf = 0; kf < 8; ++kf) {
      const int kmin = w * 128 + kf * 16;
      const int kbase = kmin + quad * 4;
      float4 at;
      float* ap = (float*)&at;
#pragma unroll
      for (int i = 0; i < 4; ++i) ap[i] = acc[kf][qf][i] * rs[qf];
      if (kmin + 15 - qgmin <= -32) {            // whole frag -> s0 bucket
#pragma unroll
        for (int i = 0; i < 4; ++i) s0p[qf] += ap[i];
      } else if (kmin - (qgmin + 15) >= 32) {    // whole frag -> s64 bucket
#pragma unroll
        for (int i = 0; i < 4; ++i) s64p[qf] += ap[i];
      } else {                                   // band frag: per-element
#pragma unroll
        for (int i = 0; i < 4; ++i) {
          int d = kbase + i - qg;
          if (d <= -32) s0p[qf] += ap[i];
          else if (d >= 32) s64p[qf] += ap[i];
          else {
            int col = d + 32;   // 1..63
            abufT[q * 64 + (((col >> 3) + q) & 7) * 8 + (col & 7)] = f2bf(ap[i]);
          }
        }
      }
      *(float4*)(&attn_out[((size_t)bh * 512 + qg) * 512 + kbase]) = at;
      uint2 pk = pack4(at);
      int cc = kbase >> 3;    // 16B chunk index within row
      *(uint2*)(&attnb[q * 512 + ((cc + q) & 63) * 8 + (quad & 1) * 4]) = pk;
    }
  }
  // bucket sums: reduce over quads then over waves
#pragma unroll
  for (int qf = 0; qf < 2; ++qf) {
    s0p[qf] += __shfl_xor(s0p[qf], 16, 64);
    s0p[qf] += __shfl_xor(s0p[qf], 32, 64);
    s64p[qf] += __shfl_xor(s64p[qf], 16, 64);
    s64p[qf] += __shfl_xor(s64p[qf], 32, 64);
  }
  if (quad == 0) {
#pragma unroll
    for (int qf = 0; qf < 2; ++qf) {
      red_s0[w * 64 + qf * 16 + lanelo] = s0p[qf];
      red_s64[w * 64 + qf * 16 + lanelo] = s64p[qf];
    }
  }
  __syncthreads();                                  // sync 5 (attnb/abufT/red ready)
  float s0f[2], s64f[2];
#pragma unroll
  for (int qf = 0; qf < 2; ++qf) {
    int q = qf * 16 + lanelo;
    s0f[qf] = red_s0[q] + red_s0[64 + q] + red_s0[128 + q] + red_s0[192 + q];
    s64f[qf] = red_s64[q] + red_s64[64 + q] + red_s64[128 + q] + red_s64[192 + q];
  }

  // ---- AV: ctx^T[d][q] = vT@attn + relT@abufT; A frags direct from global ----
  f32x4 cacc[2][2];
#pragma unroll
  for (int mf = 0; mf < 2; ++mf)
#pragma unroll
    for (int nf = 0; nf < 2; ++nf) cacc[mf][nf] = zf;
  const unsigned short* vbp = vT + (size_t)bh * 65536;
#pragma unroll
  for (int kt = 0; kt < 16; ++kt) {
    bf16x8 afr[2], bfr[2];
#pragma unroll
    for (int mf = 0; mf < 2; ++mf)
      afr[mf] = *(const bf16x8*)(vbp + (size_t)((w * 2 + mf) * 16 + lanelo) * 512 +
                                 kt * 32 + quad * 8);
#pragma unroll
    for (int nf = 0; nf < 2; ++nf) {
      int q = nf * 16 + lanelo;
      bfr[nf] = *(const bf16x8*)(&attnb[q * 512 + ((kt * 4 + quad + q) & 63) * 8]);
    }
#pragma unroll
    for (int mf = 0; mf < 2; ++mf)
#pragma unroll
      for (int nf = 0; nf < 2; ++nf) cacc[mf][nf] = MFMA16(afr[mf], bfr[nf], cacc[mf][nf]);
  }
#pragma unroll
  for (int kt = 16; kt < 18; ++kt) {
    bf16x8 afr[2], bfr[2];
#pragma unroll
    for (int mf = 0; mf < 2; ++mf)
      afr[mf] = *(const bf16x8*)(relT + ((w * 2 + mf) * 16 + lanelo) * 96 +
                                 (kt - 16) * 32 + quad * 8);
#pragma unroll
    for (int nf = 0; nf < 2; ++nf) {
      int q = nf * 16 + lanelo;
      bfr[nf] = *(const bf16x8*)(&abufT[q * 64 + (((kt - 16) * 4 + quad + q) & 7) * 8]);
    }
#pragma unroll
    for (int mf = 0; mf < 2; ++mf)
#pragma unroll
      for (int nf = 0; nf < 2; ++nf) cacc[mf][nf] = MFMA16(afr[mf], bfr[nf], cacc[mf][nf]);
  }

  // ---- epilogue: + s0*rel[0] + s64*rel[64] (fp32), packed bf16 ctx store ----
  float r0v[2][4], r64v[2][4];
#pragma unroll
  for (int mf = 0; mf < 2; ++mf)
#pragma unroll
    for (int i = 0; i < 4; ++i) {
      int d = w * 32 + mf * 16 + quad * 4 + i;
      r0v[mf][i] = relf[d];
      r64v[mf][i] = relf[64 * 128 + d];
    }
  const int b_ = bh >> 3, h_ = bh & 7;
#pragma unroll
  for (int nf = 0; nf < 2; ++nf) {
    int qg = q0 + nf * 16 + lanelo;
#pragma unroll
    for (int mf = 0; mf < 2; ++mf) {
      unsigned short ov[4];
#pragma unroll
      for (int i = 0; i < 4; ++i) {
        float val = cacc[mf][nf][i] + s0f[nf] * r0v[mf][i] + s64f[nf] * r64v[mf][i];
        ov[i] = f2bf(val);
      }
      uint2 pk;
      pk.x = (unsigned)ov[0] | ((unsigned)ov[1] << 16);
      pk.y = (unsigned)ov[2] | ((unsigned)ov[3] << 16);
      *(uint2*)(&ctx[((size_t)(b_ * 512 + qg)) * 1024 + h_ * 128 + w * 32 + mf * 16 + quad * 4]) = pk;
    }
  }
}

// ---------------------------------------------------------------------------
// K7: out = ctx @ Wo^T + bo. 128x128 tiles; ctx via DMA, Wo fp32->bf16 manual
// staging (rot8 swizzle preserved).
// ---------------------------------------------------------------------------
__global__ __launch_bounds__(256) void out_proj(
    const unsigned short* __restrict__ ctx, const float* __restrict__ Wo,
    const float* __restrict__ bo, float* __restrict__ outp) {
  __shared__ __align__(16) unsigned short As[128 * 64];
  __shared__ __align__(16) unsigned short Bs[128 * 64];
  const int bm = blockIdx.x & 31, bn = blockIdx.x >> 5;
  const int tid = threadIdx.x, lane = tid & 63, w = tid >> 6;
  const int wm = (w >> 1) * 64, wn = (w & 1) * 64;
  const int lanelo = lane & 15, quad = lane >> 4;
  const int row0 = bm * 128, col0 = bn * 128;
  const int rloc = lane >> 3, pch = lane & 7;
  const int lch = (pch - rloc) & 7;
  f32x4 acc[4][4];
  const f32x4 zf = {0.f, 0.f, 0.f, 0.f};
#pragma unroll
  for (int i = 0; i < 4; ++i)
#pragma unroll
    for (int j = 0; j < 4; ++j) acc[i][j] = zf;

  for (int kt = 0; kt < 16; ++kt) {
#pragma unroll
    for (int q = 0; q < 4; ++q) {
      int seg = w * 4 + q;
      int grow = seg * 8 + rloc;
      gld16(ctx + (size_t)(row0 + grow) * 1024 + kt * 64 + lch * 8, &As[seg * 512]);
    }
    for (int c = tid; c < 1024; c += 256) {     // Wo fp32 -> bf16, rot8
      int r = c >> 3, cc2 = c & 7;
      const float* src = Wo + (size_t)(col0 + r) * 1024 + kt * 64 + cc2 * 8;
      int pc = (cc2 + r) & 7;
      *(uint2*)(&Bs[r * 64 + pc * 8]) = pack4(*(const float4*)src);
      *(uint2*)(&Bs[r * 64 + pc * 8 + 4]) = pack4(*(const float4*)(src + 4));
    }
    __syncthreads();
#pragma unroll
    for (int ks = 0; ks < 2; ++ks) {
      const int pA = (ks * 4 + quad + lanelo) & 7;
      bf16x8 a[4], bb[4];
#pragma unroll
      for (int i = 0; i < 4; ++i)
        a[i] = *(const bf16x8*)(&As[(wm + i * 16 + lanelo) * 64 + pA * 8]);
#pragma unroll
      for (int j = 0; j < 4; ++j)
        bb[j] = *(const bf16x8*)(&Bs[(wn + j * 16 + lanelo) * 64 + pA * 8]);
#pragma unroll
      for (int i = 0; i < 4; ++i)
#pragma unroll
        for (int j = 0; j < 4; ++j) acc[i][j] = MFMA16(a[i], bb[j], acc[i][j]);
    }
    __syncthreads();
  }
#pragma unroll
  for (int i = 0; i < 4; ++i) {
#pragma unroll
    for (int j = 0; j < 4; ++j) {
      int n = col0 + wn + j * 16 + lanelo;
      float bbv = bo[n];
#pragma unroll
      for (int r = 0; r < 4; ++r) {
        int m = row0 + wm + i * 16 + quad * 4 + r;
        outp[(size_t)m * 1024 + n] = acc[i][j][r] + bbv;
      }
    }
  }
}

// ---------------------------------------------------------------------------
extern "C" void kernel_launch(void* const* d_in, const int* in_sizes, int n_in,
                              void* d_out, int out_size, void* d_ws, size_t ws_size,
                              hipStream_t stream) {
  const float* x    = (const float*)d_in[0];
  const int*   mask = (const int*)d_in[1];
  const float* Wq   = (const float*)d_in[2];
  const float* bq   = (const float*)d_in[3];
  const float* Wk   = (const float*)d_in[4];
  const float* bk   = (const float*)d_in[5];
  const float* Wv   = (const float*)d_in[6];
  const float* bv   = (const float*)d_in[7];
  const float* Wo   = (const float*)d_in[8];
  const float* bo   = (const float*)d_in[9];
  const float* rel  = (const float*)d_in[10];
  const float* Wihf = (const float*)d_in[11];
  const float* Whhf = (const float*)d_in[12];
  const float* bihf = (const float*)d_in[13];
  const float* bhhf = (const float*)d_in[14];
  const float* Wihb = (const float*)d_in[15];
  const float* Whhb = (const float*)d_in[16];
  const float* bihb = (const float*)d_in[17];
  const float* bhhb = (const float*)d_in[18];

  // ws: 33,595,648 bytes used (proven-safe <= 33,702,144)
  char* ws = (char*)d_ws;
  unsigned short* qb   = (unsigned short*)(ws + 0);          // 8,388,608 B
  unsigned short* kb   = (unsigned short*)(ws + 8388608);    // 8,388,608 B
  unsigned short* vT   = (unsigned short*)(ws + 16777216);   // 8,388,608 B
  unsigned short* ctx  = (unsigned short*)(ws + 25165824);   // 8,388,608 B
  unsigned short* relb = (unsigned short*)(ws + 33554432);   //    16,640 B
  unsigned short* relT = (unsigned short*)(ws + 33571072);   //    24,576 B

  float* outp  = (float*)d_out;
  float* attnF = outp + 4194304;                 // (B,H,S,S) fp32 = 67.1 MB
  // bf16 scratch inside the attn region; all dead before scores_av_fused
  // overwrites the whole region with fp32 attn:
  unsigned short* abase  = (unsigned short*)attnF;
  unsigned short* xb     = abase;                 // 4,194,304 elems
  unsigned short* vb     = abase + 4194304;       // 4,194,304 elems
  unsigned short* rnnout = abase + 8388608;       // 6,291,456 elems
  unsigned short* Wqkvb  = abase + 14680064;      // 3,145,728 elems
  unsigned short* Wrnnb  = abase + 17825792;      //    65,536 elems

  prep_bf16<<<dim3(7232), dim3(256), 0, stream>>>(
      x, Wq, Wk, Wv, Wihf, Whhf, Wihb, Whhb, xb, Wqkvb, Wrnnb);
  prep_rel<<<dim3(48), dim3(256), 0, stream>>>(rel, relb, relT);
  qkv_proj<<<dim3(768), dim3(256), 0, stream>>>(xb, Wqkvb, bq, bk, bv, mask,
                                                qb, kb, vb, vT);
  rnn_fused<<<dim3(768), dim3(256), 0, stream>>>(qb, kb, vb, Wrnnb,
                                                 bihf, bhhf, bihb, bhhb, rnnout);
  rnn_copyback<<<dim3(24576), dim3(256), 0, stream>>>(rnnout, qb, kb, vT);
  scores_av_fused<<<dim3(1024), dim3(256), 0, stream>>>(qb, kb, relb, vT, relT,
                                                        rel, mask, attnF, ctx);
  out_proj<<<dim3(256), dim3(256), 0, stream>>>(ctx, Wo, bo, outp);
}